// Round 19
// baseline (236.492 us; speedup 1.0000x reference)
//
#include <hip/hip_runtime.h>

// Problem constants (B=2, S=2048, HIDDEN=1024, HEADS=16, HEAD_DIM=64, ROT=16)
#define S_ 2048
#define EPSF 1e-8f
#define SCALEF 0.125f

typedef short bf16x8 __attribute__((ext_vector_type(8)));
typedef float f32x4 __attribute__((ext_vector_type(4)));

__device__ __forceinline__ unsigned short f2bf(float f){
  unsigned int u = __float_as_uint(f);
  u = (u + 0x7fffu + ((u >> 16) & 1u)) >> 16;
  return (unsigned short)u;
}
__device__ __forceinline__ float bf2f(unsigned short h){
  return __uint_as_float(((unsigned int)h) << 16);
}
__device__ __forceinline__ unsigned short f2bf_trunc(float f){
  return (unsigned short)(__float_as_uint(f) >> 16);
}

#define GLD16(g, l) __builtin_amdgcn_global_load_lds( \
    (const __attribute__((address_space(1))) unsigned int*)(g), \
    (__attribute__((address_space(3))) unsigned int*)(l), 16, 0, 0)

// ---------------- 1: merged prep (conv_a | conv_wt | v0+U | zero c_c)
__global__ void k_prep(const float* __restrict__ hs, const float* __restrict__ Wqkv,
                       const float* __restrict__ bqkv, const float* __restrict__ Wd,
                       unsigned short* __restrict__ Ab,
                       unsigned short* __restrict__ WT,
                       float* __restrict__ U,
                       float* __restrict__ c_c){
  __shared__ float t[32][33];     // conv_wt path
  __shared__ float red[4][64];    // v0 path
  __shared__ float vsh[64];
  int bid = blockIdx.x;
  if (bid < 4096){
    int i = (bid * 256 + threadIdx.x) * 4;
    float4 v = *(const float4*)(hs + i);
    ushort4 o; o.x=f2bf(v.x); o.y=f2bf(v.y); o.z=f2bf(v.z); o.w=f2bf(v.w);
    *(ushort4*)(Ab + i) = o;
  } else if (bid < 6144){
    int q = bid - 4096;
    int nt = q & 63, kt = q >> 6;
    int tx = threadIdx.x & 31, ty = threadIdx.x >> 5;   // 32 x 8
    #pragma unroll
    for (int r = 0; r < 32; r += 8)
      t[ty + r][tx] = Wqkv[(size_t)(kt*32 + ty + r)*3072 + nt*32 + tx];
    __syncthreads();
    #pragma unroll
    for (int r = 0; r < 32; r += 8)
      WT[(size_t)(nt*32 + ty + r)*1024 + kt*32 + tx] = f2bf(t[tx][ty + r]);
  } else if (bid < 6176){
    // v0 = hs[b,0,:] @ Wqkv[:,2048+h*64+:] + b; then U = v0 @ Wd rows
    int bh = bid - 6144; int b = bh >> 4, h = bh & 15;
    int d = threadIdx.x & 63, kc = threadIdx.x >> 6;
    const float* x = hs + (size_t)b * S_ * 1024;
    int col = 2048 + h*64 + d;
    float acc = 0.f;
    #pragma unroll 8
    for (int k = kc*256; k < kc*256 + 256; ++k)
      acc = fmaf(x[k], Wqkv[(size_t)k*3072 + col], acc);
    red[kc][d] = acc;
    __syncthreads();
    if (kc == 0)
      vsh[d] = red[0][d] + red[1][d] + red[2][d] + red[3][d] + bqkv[col];
    __syncthreads();
    for (int n = threadIdx.x; n < 1024; n += 256){
      float a2 = 0.f;
      #pragma unroll 8
      for (int dd = 0; dd < 64; ++dd)
        a2 = fmaf(vsh[dd], Wd[(size_t)(h*64 + dd)*1024 + n], a2);
      U[(size_t)bh*1024 + n] = a2;
    }
  } else {
    // zero c_c: 64 blocks x 4KB = 256KB
    int q = bid - 6176;
    float4 z = (float4){0.f,0.f,0.f,0.f};
    *(float4*)(c_c + (size_t)q*1024 + threadIdx.x*4) = z;
  }
}

// ---------------- 2: QK projection GEMM + fused RoPE epilogue (m97 staging).
#define BK 32
__launch_bounds__(256)
__global__ void k_gemm_qk(const unsigned short* __restrict__ Ab,
                          const unsigned short* __restrict__ WT,
                          const float* __restrict__ bqkv,
                          const int* __restrict__ pos_ids,
                          unsigned short* __restrict__ Qb,
                          unsigned short* __restrict__ Kb){
  __shared__ unsigned short At[128*BK];   // 8 KB, linear
  __shared__ unsigned short Bt[128*BK];   // 8 KB, linear
  const int m0 = blockIdx.y * 128, n0 = blockIdx.x * 128;
  const int w = threadIdx.x >> 6, l = threadIdx.x & 63;
  const int wr = w >> 1, wc = w & 1;
  const int lq = l & 15, lh = l >> 4;
  f32x4 acc[4][4];
  #pragma unroll
  for (int i = 0; i < 4; ++i)
    #pragma unroll
    for (int j = 0; j < 4; ++j) acc[i][j] = (f32x4){0.f,0.f,0.f,0.f};

  const int srow = l >> 2;
  const int scol = (l & 3) * 8;

  for (int kt = 0; kt < 1024; kt += BK){
    GLD16(Ab + (size_t)(m0 + w*32 +      srow)*1024 + kt + scol, &At[(w*32)*BK]);
    GLD16(Ab + (size_t)(m0 + w*32 + 16 + srow)*1024 + kt + scol, &At[(w*32+16)*BK]);
    GLD16(WT + (size_t)(n0 + w*32 +      srow)*1024 + kt + scol, &Bt[(w*32)*BK]);
    GLD16(WT + (size_t)(n0 + w*32 + 16 + srow)*1024 + kt + scol, &Bt[(w*32+16)*BK]);
    __syncthreads();
    bf16x8 af[4], bf[4];
    #pragma unroll
    for (int i = 0; i < 4; ++i)
      af[i] = *(const bf16x8*)&At[(wr*64 + i*16 + lq)*BK + lh*8];
    #pragma unroll
    for (int j = 0; j < 4; ++j)
      bf[j] = *(const bf16x8*)&Bt[(wc*64 + j*16 + lq)*BK + lh*8];
    #pragma unroll
    for (int i = 0; i < 4; ++i)
      #pragma unroll
      for (int j = 0; j < 4; ++j)
        acc[i][j] = __builtin_amdgcn_mfma_f32_16x16x32_bf16(af[i], bf[j], acc[i][j], 0, 0, 0);
    __syncthreads();
  }
  #pragma unroll
  for (int i = 0; i < 4; ++i){
    #pragma unroll
    for (int j = 0; j < 4; ++j){
      #pragma unroll
      for (int r = 0; r < 4; ++r){
        int m = m0 + wr*64 + i*16 + (l>>4)*4 + r;
        int n = n0 + wc*64 + j*16 + (l&15);
        float v = acc[i][j][r] + bqkv[n];
        if (j == 0){   // rotary dims d = lq < 16
          float partner = __shfl_xor(v, 8);
          int s = m & 2047;
          float pos = (float)pos_ids[s];
          float fr = exp2f(-1.6609640474436813f * (float)(l & 7));
          float th = pos * fr;
          float sn = __sinf(th), cn = __cosf(th);
          v = ((l & 8) == 0) ? (v*cn - partner*sn) : (v*cn + partner*sn);
        }
        int b = m >> 11, s2 = m & 2047;
        int tsel = n >> 10; int nq = n & 1023;
        int h = nq >> 6, d = nq & 63;
        unsigned short* dst = tsel ? Kb : Qb;
        dst[((size_t)(b*16 + h)*S_ + s2)*64 + d] = f2bf(v);
      }
    }
  }
}

// ---------------- 4a: E + rinv + Dinv, balanced pairing.
// 512 WGs: p = blk>>5 in [0,16), bh = blk&31. Phase 0: bi=p, phase 1: bi=31-p
// -> exactly 33 tiles per WG, 66 per CU on every CU (was 52-80).
// Per phase epilogue: rinv (as before) then FUSED Dinv (was k_dinv): As
// overlays dead Ks (16.6 <= 16.9 KB), wave0 forward-substitutes, writes Dg.
// Bitwise-identical Dinv inputs (bf16 E from Es, same rinv) -> absmax same.
#define KST2 66
#define EST 68
__launch_bounds__(256, 4)
__global__ void k_scores(const unsigned short* __restrict__ Qb,
                         const unsigned short* __restrict__ Kb,
                         unsigned short* __restrict__ Eg,
                         float* __restrict__ rinvg,
                         unsigned short* __restrict__ Dg){
  __shared__ unsigned short Ks[2][64*KST2] __attribute__((aligned(16)));
  __shared__ unsigned short Es[4][16*EST];
  __shared__ float dsh[4][16];
  __shared__ float rvs[64];
  float* As = (float*)&Ks[0][0];           // overlay: 64*65*4B = 16640 <= 16896
  const int p = blockIdx.x >> 5, bh = blockIdx.x & 31;
  const unsigned short* Qh = Qb + (size_t)bh * S_ * 64;
  const unsigned short* Kh = Kb + (size_t)bh * S_ * 64;
  const int tid = threadIdx.x, w = tid >> 6, l = tid & 63;
  const int lq = l & 15, lh = l >> 4;
  const int srow = tid >> 2, sc = (tid & 3)*16;

  for (int ph = 0; ph < 2; ++ph){
    const int bi = ph ? (31 - p) : p;
    const unsigned short* qp = Qh + (size_t)(bi*64 + w*16 + lq)*64 + lh*8;
    bf16x8 qf0 = *(const bf16x8*)(qp);
    bf16x8 qf1 = *(const bf16x8*)(qp + 32);
    float dacc[4] = {0.f,0.f,0.f,0.f};
    unsigned short* Etile0 = Eg + ((size_t)bh*528 + (size_t)(bi*(bi+1)/2))*4096;

    { // prologue: stage K block 0 into buf 0 (Ks free: As fully consumed)
      const unsigned short* src = Kh + (size_t)srow*64 + sc;
      *(int4*)&Ks[0][srow*KST2 + sc]     = *(const int4*)(src);
      *(int4*)&Ks[0][srow*KST2 + sc + 8] = *(const int4*)(src + 8);
    }
    __syncthreads();

    for (int bj = 0; bj <= bi; ++bj){
      const int cur = bj & 1;
      int4 nk0, nk1;
      if (bj < bi){
        const unsigned short* src = Kh + (size_t)((bj+1)*64 + srow)*64 + sc;
        nk0 = *(const int4*)(src);
        nk1 = *(const int4*)(src + 8);
      }
      unsigned short* Et = Etile0 + (size_t)bj*4096 + w*1024;
      const bool diag = (bj == bi);
      #pragma unroll
      for (int ct = 0; ct < 4; ++ct){
        bf16x8 b0 = *(const bf16x8*)&Ks[cur][(ct*16 + lq)*KST2 + lh*8];
        bf16x8 b1 = *(const bf16x8*)&Ks[cur][(ct*16 + lq)*KST2 + 32 + lh*8];
        f32x4 a = (f32x4){0.f,0.f,0.f,0.f};
        a = __builtin_amdgcn_mfma_f32_16x16x32_bf16(qf0, b0, a, 0, 0, 0);
        a = __builtin_amdgcn_mfma_f32_16x16x32_bf16(qf1, b1, a, 0, 0, 0);
        #pragma unroll
        for (int r = 0; r < 4; ++r){
          float e = __expf(a[r] * SCALEF);
          unsigned short eb = f2bf_trunc(e);
          int rrow = lh*4 + r, col = ct*16 + lq;
          Es[w][rrow*EST + col] = eb;
          float ev = bf2f(eb);
          int grow = w*16 + rrow;
          if (!diag || col < grow) dacc[r] += ev;
          if (diag && col == grow) dsh[w][rrow] = ev;
        }
      }
      #pragma unroll
      for (int it = 0; it < 2; ++it){
        int row = it*8 + (l >> 3), eo = (l & 7)*8;
        *(int4*)(Et + row*64 + eo) = *(const int4*)&Es[w][row*EST + eo];
      }
      if (bj < bi){
        *(int4*)&Ks[cur^1][srow*KST2 + sc]     = nk0;
        *(int4*)&Ks[cur^1][srow*KST2 + sc + 8] = nk1;
      }
      __syncthreads();
    }
    // rinv epilogue
    #pragma unroll
    for (int r = 0; r < 4; ++r){
      float d = dacc[r];
      #pragma unroll
      for (int mm = 1; mm < 16; mm <<= 1) d += __shfl_xor(d, mm);
      float dE = dsh[w][lh*4 + r];
      float den = fmaf(EPSF, d + dE, d);
      float rv = 1.0f / den;
      if (lq == 0){
        rinvg[(size_t)bh*S_ + bi*64 + w*16 + lh*4 + r] = rv;
        rvs[w*16 + lh*4 + r] = rv;
      }
    }
    __syncthreads();   // rvs + Es(diag) ready; Ks dead -> As build
    { // As[r*65+c] = (c<r) ? E[r][c]*rinv_r : 0  (256 threads x 16 entries)
      int r = tid >> 2, c0 = (tid & 3)*16;
      float rv = rvs[r];
      #pragma unroll
      for (int cc = 0; cc < 16; ++cc){
        int c = c0 + cc;
        float e = bf2f(Es[r >> 4][(r & 15)*EST + c]);
        As[r*65 + c] = (c < r) ? e * rv : 0.f;
      }
    }
    __syncthreads();
    if (w == 0){   // forward substitution, lane = column c
      const int c = l;
      float X[64];
      #pragma unroll
      for (int r = 0; r < 64; ++r){
        float acc = (r == c) ? 1.f : 0.f;
        #pragma unroll
        for (int k = 0; k < r; ++k)
          acc = fmaf(As[r*65 + k], X[k], acc);
        X[r] = acc;
      }
      unsigned short* dt = Dg + (size_t)(bh*32 + bi) * 4096;
      #pragma unroll
      for (int r = 0; r < 64; ++r)
        dt[(r>>4)*1024 + (r&15)*64 + c] = f2bf(X[r]);
    }
    __syncthreads();   // As consumed before next phase re-stages Ks
  }
}

// ---------------- 4b: striped recurrence v4 — 8 stripes/head (256 WGs).
// (unchanged from R17 — known-good)
__global__ __launch_bounds__(512)
__attribute__((amdgpu_waves_per_eu(2, 2)))
void k_recur3(const unsigned short* __restrict__ Eg,
              const unsigned short* __restrict__ Dg,
              const float* __restrict__ rinvg,
              float* __restrict__ c_c,
              float* __restrict__ c_g){
  __shared__ float Pa[256];     // owned block o at Pa[o*64+row]
  __shared__ float rso[256];
  __shared__ float csl[2][64];
  __shared__ float bb[64];
  const int bh = blockIdx.x & 31, s = blockIdx.x >> 5;
  const unsigned short* Eh = Eg + (size_t)bh * 528 * 4096;
  const int tid = threadIdx.x, w = tid >> 6, l = tid & 63;
  const int lq = l & 15, lh = l >> 4;

  if (tid < 256){
    Pa[tid] = 0.f;
    rso[tid] = rinvg[(size_t)bh*S_ + (s + 8*(tid >> 6))*64 + l];
  }
  __syncthreads();

  bf16x8 dv0[4], dv1[4];        // wave0: Dinv tile of next owned block
  if (w == 0){
    const unsigned short* dt = Dg + (size_t)(bh*32 + s)*4096;
    #pragma unroll
    for (int q = 0; q < 4; ++q){
      dv0[q] = *(const bf16x8*)(dt + q*1024 + lq*64 + lh*8);
      dv1[q] = *(const bf16x8*)(dt + q*1024 + lq*64 + 32 + lh*8);
    }
  }

  bf16x8 dA0[3], dA1[3], dB0[3], dB1[3];   // deferred staging ping-pong
  bf16x8 ug0, ug1;                          // urgent tile regs (waves 1-4)
  const int lastc = s + 24;

  auto load_def = [&](int BJ, bf16x8 (&D0)[3], bf16x8 (&D1)[3]){
    int o0 = (BJ >= s) ? (((BJ - s) >> 3) + 1) : 0;
    int ex = (((BJ + 1) & 7) == s) ? 1 : 0;
    int nd = (4 - o0 - ex) * 4;
    if (w >= 1){
      #pragma unroll
      for (int k = 0; k < 3; ++k){
        int t = (w - 1) + k*7;
        if (t < nd){
          int ob = o0 + ex + (t >> 2);
          int bi = s + 8*ob;
          const unsigned short* tp =
              Eh + ((size_t)(bi*(bi+1)/2) + BJ)*4096 + (size_t)(t & 3)*1024;
          D0[k] = *(const bf16x8*)(tp + lq*64 + lh*8);
          D1[k] = *(const bf16x8*)(tp + lq*64 + 32 + lh*8);
        }
      }
      if (ex && w <= 4){
        int bi = BJ + 1;
        const unsigned short* tp =
            Eh + ((size_t)(bi*(bi+1)/2) + BJ)*4096 + (size_t)(w-1)*1024;
        ug0 = *(const bf16x8*)(tp + lq*64 + lh*8);
        ug1 = *(const bf16x8*)(tp + lq*64 + 32 + lh*8);
      }
    }
  };

  auto fold_def = [&](int BJP, bf16x8 (&D0)[3], bf16x8 (&D1)[3], int buf){
    int o0 = (BJP >= s) ? (((BJP - s) >> 3) + 1) : 0;
    int ex = (((BJP + 1) & 7) == s) ? 1 : 0;
    int nd = (4 - o0 - ex) * 4;
    if (w >= 1 && nd > 0){
      bf16x8 dc0 = (bf16x8){0,0,0,0,0,0,0,0};
      bf16x8 dc1 = (bf16x8){0,0,0,0,0,0,0,0};
      if (lq == 0){
        #pragma unroll
        for (int e = 0; e < 8; ++e){
          dc0[e] = (short)f2bf(csl[buf][lh*8 + e]);
          dc1[e] = (short)f2bf(csl[buf][32 + lh*8 + e]);
        }
      }
      #pragma unroll
      for (int k = 0; k < 3; ++k){
        int t = (w - 1) + k*7;
        if (t < nd){
          f32x4 o = (f32x4){0.f,0.f,0.f,0.f};
          o = __builtin_amdgcn_mfma_f32_16x16x32_bf16(D0[k], dc0, o, 0, 0, 0);
          o = __builtin_amdgcn_mfma_f32_16x16x32_bf16(D1[k], dc1, o, 0, 0, 0);
          if (lq == 0){
            int ob = o0 + ex + (t >> 2);
            float* base = Pa + ob*64 + (t & 3)*16 + lh*4;
            float4 v = *(float4*)base;
            v.x += o[0]; v.y += o[1]; v.z += o[2]; v.w += o[3];
            *(float4*)base = v;
          }
        }
      }
    }
  };

  auto iter = [&](int BJ, bf16x8 (&DL0)[3], bf16x8 (&DL1)[3],
                          bf16x8 (&DF0)[3], bf16x8 (&DF1)[3]){
    const int cur = BJ & 1;
    load_def(BJ, DL0, DL1);
    const int ex = (((BJ + 1) & 7) == s) ? 1 : 0;
    if (w == 0){
      if ((BJ & 7) == s){
        // matvec solve: c_blk = Dinv @ (rinv .* Pa), b0 := 1 at global row 0
        const int o = (BJ - s) >> 3;
        float bval = rso[o*64 + l] * Pa[o*64 + l];
        if (BJ == 0 && l == 0) bval = 1.0f;
        bb[l] = bval;
        bf16x8 uc0 = (bf16x8){0,0,0,0,0,0,0,0};
        bf16x8 uc1 = (bf16x8){0,0,0,0,0,0,0,0};
        if (lq == 0){
          #pragma unroll
          for (int e = 0; e < 8; ++e){
            uc0[e] = (short)f2bf(bb[lh*8 + e]);
            uc1[e] = (short)f2bf(bb[32 + lh*8 + e]);
          }
        }
        #pragma unroll
        for (int q = 0; q < 4; ++q){
          f32x4 o4 = (f32x4){0.f,0.f,0.f,0.f};
          o4 = __builtin_amdgcn_mfma_f32_16x16x32_bf16(dv0[q], uc0, o4, 0, 0, 0);
          o4 = __builtin_amdgcn_mfma_f32_16x16x32_bf16(dv1[q], uc1, o4, 0, 0, 0);
          if (lq == 0){
            #pragma unroll
            for (int r = 0; r < 4; ++r)
              csl[cur][q*16 + lh*4 + r] = o4[r];
          }
        }
        float cval = csl[cur][l];
        __hip_atomic_store((unsigned*)(c_c + (size_t)bh*S_ + BJ*64 + l),
                           __float_as_uint(cval),
                           __ATOMIC_RELAXED, __HIP_MEMORY_SCOPE_AGENT);
        c_g[((size_t)(bh >> 4)*S_ + (BJ*64 + l))*16 + (bh & 15)] = cval;
        int bn = BJ + 8;            // prefetch next owned Dinv tile
        if (bn <= lastc){
          const unsigned short* dt = Dg + (size_t)(bh*32 + bn)*4096;
          #pragma unroll
          for (int q = 0; q < 4; ++q){
            dv0[q] = *(const bf16x8*)(dt + q*1024 + lq*64 + lh*8);
            dv1[q] = *(const bf16x8*)(dt + q*1024 + lq*64 + 32 + lh*8);
          }
        }
      } else {
        const unsigned* pp = (const unsigned*)(c_c + (size_t)bh*S_ + BJ*64 + l);
        unsigned v = __hip_atomic_load(pp, __ATOMIC_RELAXED,
                                       __HIP_MEMORY_SCOPE_AGENT);
        while (!__all(v != 0u)){
          __builtin_amdgcn_s_sleep(2);
          v = __hip_atomic_load(pp, __ATOMIC_RELAXED,
                                __HIP_MEMORY_SCOPE_AGENT);
        }
        csl[cur][l] = __uint_as_float(v);
      }
    } else if (BJ >= 1){
      fold_def(BJ - 1, DF0, DF1, cur ^ 1);
    }
    __syncthreads();
    // phase B: urgent fold (col BJ -> block BJ+1), waves 1-4
    if (ex && w >= 1 && w <= 4){
      bf16x8 uc0 = (bf16x8){0,0,0,0,0,0,0,0};
      bf16x8 uc1 = (bf16x8){0,0,0,0,0,0,0,0};
      if (lq == 0){
        #pragma unroll
        for (int e = 0; e < 8; ++e){
          uc0[e] = (short)f2bf(csl[cur][lh*8 + e]);
          uc1[e] = (short)f2bf(csl[cur][32 + lh*8 + e]);
        }
      }
      f32x4 o = (f32x4){0.f,0.f,0.f,0.f};
      o = __builtin_amdgcn_mfma_f32_16x16x32_bf16(ug0, uc0, o, 0, 0, 0);
      o = __builtin_amdgcn_mfma_f32_16x16x32_bf16(ug1, uc1, o, 0, 0, 0);
      if (lq == 0){
        int ou = (BJ + 1 - s) >> 3;
        float* base = Pa + ou*64 + (w-1)*16 + lh*4;
        float4 v = *(float4*)base;
        v.x += o[0]; v.y += o[1]; v.z += o[2]; v.w += o[3];
        *(float4*)base = v;
      }
    }
    __syncthreads();
  };

  for (int bj = 0; bj <= lastc; bj += 2){
    iter(bj,     dA0, dA1, dB0, dB1);
    if (bj + 1 <= lastc)
      iter(bj+1, dB0, dB1, dA0, dA1);
  }
}

// ---------------- 5: out[b,s,n] = bd[n] + sum_h c[b,s,h] * U[b,h,n]
__global__ void k_out(const float* __restrict__ c_g, const float* __restrict__ U,
                      const float* __restrict__ bd, float* __restrict__ out){
  int bs = blockIdx.x; int b = bs >> 11;
  __shared__ float ch[16];
  if (threadIdx.x < 16) ch[threadIdx.x] = c_g[(size_t)bs*16 + threadIdx.x];
  __syncthreads();
  int n = threadIdx.x * 4;
  float4 acc = *(const float4*)(bd + n);
  #pragma unroll
  for (int h = 0; h < 16; ++h){
    float cc = ch[h];
    float4 u = *(const float4*)(U + ((size_t)(b*16 + h))*1024 + n);
    acc.x = fmaf(cc, u.x, acc.x); acc.y = fmaf(cc, u.y, acc.y);
    acc.z = fmaf(cc, u.z, acc.z); acc.w = fmaf(cc, u.w, acc.w);
  }
  *(float4*)(out + (size_t)bs*1024 + n) = acc;
}

extern "C" void kernel_launch(void* const* d_in, const int* in_sizes, int n_in,
                              void* d_out, int out_size, void* d_ws, size_t ws_size,
                              hipStream_t stream) {
  const float* hs   = (const float*)d_in[0];   // [2][2048][1024]
  const int*   pos  = (const int*)d_in[1];     // [2048]
  const float* Wqkv = (const float*)d_in[2];   // [1024][3072]
  const float* bqkv = (const float*)d_in[3];   // [3072]
  const float* Wd   = (const float*)d_in[4];   // [1024][1024]
  const float* bd   = (const float*)d_in[5];   // [1024]
  float* out = (float*)d_out;

  // workspace layout. Dg overlays Ab (dead after k_gemm_qk).
  char* ws = (char*)d_ws;
  unsigned short* Ab = (unsigned short*)(ws);                       // 8 MB
  unsigned short* Dg = (unsigned short*)(ws);                       // 8 MB (reuse)
  unsigned short* WT = (unsigned short*)(ws + (8u<<20));            // 4 MB
  unsigned short* Qb = (unsigned short*)(ws + (12u<<20));           // 8 MB
  unsigned short* Kb = (unsigned short*)(ws + (20u<<20));           // 8 MB
  float* c_g  = (float*)(ws + (28u<<20) + 0x10000);                 // 256 KB
  float* U    = (float*)(ws + (28u<<20) + 0x50000);                 // 128 KB
  float* rinvg= (float*)(ws + (28u<<20) + 0x80000);                 // 256 KB
  float* c_c  = (float*)(ws + (28u<<20) + 0xC0000);                 // 256 KB
  unsigned short* Eg = (unsigned short*)(ws + (29u<<20));           // 132 MB

  k_prep   <<<6240, 256, 0, stream>>>(hs, Wqkv, bqkv, Wd, Ab, WT, U, c_c);
  k_gemm_qk<<<dim3(16, 32), 256, 0, stream>>>(Ab, WT, bqkv, pos, Qb, Kb);
  k_scores <<<512, 256, 0, stream>>>(Qb, Kb, Eg, rinvg, Dg);
  k_recur3 <<<256, 512, 0, stream>>>(Eg, Dg, rinvg, c_c, c_g);
  k_out    <<<4096, 256, 0, stream>>>(c_g, U, bd, out);
}

// Round 20
// 177.639 us; speedup vs baseline: 1.3313x; 1.3313x over previous
//
#include <hip/hip_runtime.h>

// Problem constants (B=2, S=2048, HIDDEN=1024, HEADS=16, HEAD_DIM=64, ROT=16)
#define S_ 2048
#define EPSF 1e-8f
#define SCALEF 0.125f

typedef short bf16x8 __attribute__((ext_vector_type(8)));
typedef float f32x4 __attribute__((ext_vector_type(4)));

__device__ __forceinline__ unsigned short f2bf(float f){
  unsigned int u = __float_as_uint(f);
  u = (u + 0x7fffu + ((u >> 16) & 1u)) >> 16;
  return (unsigned short)u;
}
__device__ __forceinline__ float bf2f(unsigned short h){
  return __uint_as_float(((unsigned int)h) << 16);
}
__device__ __forceinline__ unsigned short f2bf_trunc(float f){
  return (unsigned short)(__float_as_uint(f) >> 16);
}

#define GLD16(g, l) __builtin_amdgcn_global_load_lds( \
    (const __attribute__((address_space(1))) unsigned int*)(g), \
    (__attribute__((address_space(3))) unsigned int*)(l), 16, 0, 0)

// ---------------- 1: merged prep (conv_a | conv_wt | v0+U | zero c_c)
__global__ void k_prep(const float* __restrict__ hs, const float* __restrict__ Wqkv,
                       const float* __restrict__ bqkv, const float* __restrict__ Wd,
                       unsigned short* __restrict__ Ab,
                       unsigned short* __restrict__ WT,
                       float* __restrict__ U,
                       float* __restrict__ c_c){
  __shared__ float t[32][33];     // conv_wt path
  __shared__ float red[4][64];    // v0 path
  __shared__ float vsh[64];
  int bid = blockIdx.x;
  if (bid < 4096){
    int i = (bid * 256 + threadIdx.x) * 4;
    float4 v = *(const float4*)(hs + i);
    ushort4 o; o.x=f2bf(v.x); o.y=f2bf(v.y); o.z=f2bf(v.z); o.w=f2bf(v.w);
    *(ushort4*)(Ab + i) = o;
  } else if (bid < 6144){
    int q = bid - 4096;
    int nt = q & 63, kt = q >> 6;
    int tx = threadIdx.x & 31, ty = threadIdx.x >> 5;   // 32 x 8
    #pragma unroll
    for (int r = 0; r < 32; r += 8)
      t[ty + r][tx] = Wqkv[(size_t)(kt*32 + ty + r)*3072 + nt*32 + tx];
    __syncthreads();
    #pragma unroll
    for (int r = 0; r < 32; r += 8)
      WT[(size_t)(nt*32 + ty + r)*1024 + kt*32 + tx] = f2bf(t[tx][ty + r]);
  } else if (bid < 6176){
    // v0 = hs[b,0,:] @ Wqkv[:,2048+h*64+:] + b; then U = v0 @ Wd rows
    int bh = bid - 6144; int b = bh >> 4, h = bh & 15;
    int d = threadIdx.x & 63, kc = threadIdx.x >> 6;
    const float* x = hs + (size_t)b * S_ * 1024;
    int col = 2048 + h*64 + d;
    float acc = 0.f;
    #pragma unroll 8
    for (int k = kc*256; k < kc*256 + 256; ++k)
      acc = fmaf(x[k], Wqkv[(size_t)k*3072 + col], acc);
    red[kc][d] = acc;
    __syncthreads();
    if (kc == 0)
      vsh[d] = red[0][d] + red[1][d] + red[2][d] + red[3][d] + bqkv[col];
    __syncthreads();
    for (int n = threadIdx.x; n < 1024; n += 256){
      float a2 = 0.f;
      #pragma unroll 8
      for (int dd = 0; dd < 64; ++dd)
        a2 = fmaf(vsh[dd], Wd[(size_t)(h*64 + dd)*1024 + n], a2);
      U[(size_t)bh*1024 + n] = a2;
    }
  } else {
    // zero c_c: 64 blocks x 4KB = 256KB
    int q = bid - 6176;
    float4 z = (float4){0.f,0.f,0.f,0.f};
    *(float4*)(c_c + (size_t)q*1024 + threadIdx.x*4) = z;
  }
}

// ---------------- 2: QK projection GEMM + fused RoPE epilogue (m97 staging).
#define BK 32
__launch_bounds__(256)
__global__ void k_gemm_qk(const unsigned short* __restrict__ Ab,
                          const unsigned short* __restrict__ WT,
                          const float* __restrict__ bqkv,
                          const int* __restrict__ pos_ids,
                          unsigned short* __restrict__ Qb,
                          unsigned short* __restrict__ Kb){
  __shared__ unsigned short At[128*BK];   // 8 KB, linear
  __shared__ unsigned short Bt[128*BK];   // 8 KB, linear
  const int m0 = blockIdx.y * 128, n0 = blockIdx.x * 128;
  const int w = threadIdx.x >> 6, l = threadIdx.x & 63;
  const int wr = w >> 1, wc = w & 1;
  const int lq = l & 15, lh = l >> 4;
  f32x4 acc[4][4];
  #pragma unroll
  for (int i = 0; i < 4; ++i)
    #pragma unroll
    for (int j = 0; j < 4; ++j) acc[i][j] = (f32x4){0.f,0.f,0.f,0.f};

  const int srow = l >> 2;
  const int scol = (l & 3) * 8;

  for (int kt = 0; kt < 1024; kt += BK){
    GLD16(Ab + (size_t)(m0 + w*32 +      srow)*1024 + kt + scol, &At[(w*32)*BK]);
    GLD16(Ab + (size_t)(m0 + w*32 + 16 + srow)*1024 + kt + scol, &At[(w*32+16)*BK]);
    GLD16(WT + (size_t)(n0 + w*32 +      srow)*1024 + kt + scol, &Bt[(w*32)*BK]);
    GLD16(WT + (size_t)(n0 + w*32 + 16 + srow)*1024 + kt + scol, &Bt[(w*32+16)*BK]);
    __syncthreads();
    bf16x8 af[4], bf[4];
    #pragma unroll
    for (int i = 0; i < 4; ++i)
      af[i] = *(const bf16x8*)&At[(wr*64 + i*16 + lq)*BK + lh*8];
    #pragma unroll
    for (int j = 0; j < 4; ++j)
      bf[j] = *(const bf16x8*)&Bt[(wc*64 + j*16 + lq)*BK + lh*8];
    #pragma unroll
    for (int i = 0; i < 4; ++i)
      #pragma unroll
      for (int j = 0; j < 4; ++j)
        acc[i][j] = __builtin_amdgcn_mfma_f32_16x16x32_bf16(af[i], bf[j], acc[i][j], 0, 0, 0);
    __syncthreads();
  }
  #pragma unroll
  for (int i = 0; i < 4; ++i){
    #pragma unroll
    for (int j = 0; j < 4; ++j){
      #pragma unroll
      for (int r = 0; r < 4; ++r){
        int m = m0 + wr*64 + i*16 + (l>>4)*4 + r;
        int n = n0 + wc*64 + j*16 + (l&15);
        float v = acc[i][j][r] + bqkv[n];
        if (j == 0){   // rotary dims d = lq < 16
          float partner = __shfl_xor(v, 8);
          int s = m & 2047;
          float pos = (float)pos_ids[s];
          float fr = exp2f(-1.6609640474436813f * (float)(l & 7));
          float th = pos * fr;
          float sn = __sinf(th), cn = __cosf(th);
          v = ((l & 8) == 0) ? (v*cn - partner*sn) : (v*cn + partner*sn);
        }
        int b = m >> 11, s2 = m & 2047;
        int tsel = n >> 10; int nq = n & 1023;
        int h = nq >> 6, d = nq & 63;
        unsigned short* dst = tsel ? Kb : Qb;
        dst[((size_t)(b*16 + h)*S_ + s2)*64 + d] = f2bf(v);
      }
    }
  }
}

// ---------------- 4a: full-chip E + rinv precompute (R17 v2 + balanced bi).
// 1024 WGs. bi = pi(blockIdx>>5) where pi: k=q>>3, m=q&7 ->
// {m, 15-m, 16+m, 31-m}. Each CU's 4 resident q's form a coset {m,m+8,m+16,
// m+24} whose pi-images sum to 62 -> exactly 66 tiles per CU (was 52-80).
#define KST2 66
#define EST 68
__launch_bounds__(256, 4)
__global__ void k_scores(const unsigned short* __restrict__ Qb,
                         const unsigned short* __restrict__ Kb,
                         unsigned short* __restrict__ Eg,
                         float* __restrict__ rinvg){
  __shared__ unsigned short Ks[2][64*KST2];
  __shared__ unsigned short Es[4][16*EST];
  __shared__ float dsh[4][16];
  const int q = blockIdx.x >> 5, bh = blockIdx.x & 31;
  const int qm = q & 7, qk = q >> 3;
  const int bi = (qk == 0) ? qm : (qk == 1) ? (15 - qm)
               : (qk == 2) ? (16 + qm) : (31 - qm);
  const unsigned short* Qh = Qb + (size_t)bh * S_ * 64;
  const unsigned short* Kh = Kb + (size_t)bh * S_ * 64;
  const int tid = threadIdx.x, w = tid >> 6, l = tid & 63;
  const int lq = l & 15, lh = l >> 4;
  const unsigned short* qp = Qh + (size_t)(bi*64 + w*16 + lq)*64 + lh*8;
  bf16x8 qf0 = *(const bf16x8*)(qp);
  bf16x8 qf1 = *(const bf16x8*)(qp + 32);
  float dacc[4] = {0.f,0.f,0.f,0.f};
  unsigned short* Etile0 = Eg + ((size_t)bh*528 + (size_t)(bi*(bi+1)/2))*4096;
  const int srow = tid >> 2, sc = (tid & 3)*16;

  {
    const unsigned short* src = Kh + (size_t)srow*64 + sc;
    *(int4*)&Ks[0][srow*KST2 + sc]     = *(const int4*)(src);
    *(int4*)&Ks[0][srow*KST2 + sc + 8] = *(const int4*)(src + 8);
  }
  __syncthreads();

  for (int bj = 0; bj <= bi; ++bj){
    const int cur = bj & 1;
    int4 nk0, nk1;
    if (bj < bi){
      const unsigned short* src = Kh + (size_t)((bj+1)*64 + srow)*64 + sc;
      nk0 = *(const int4*)(src);
      nk1 = *(const int4*)(src + 8);
    }
    unsigned short* Et = Etile0 + (size_t)bj*4096 + w*1024;
    const bool diag = (bj == bi);
    #pragma unroll
    for (int ct = 0; ct < 4; ++ct){
      bf16x8 b0 = *(const bf16x8*)&Ks[cur][(ct*16 + lq)*KST2 + lh*8];
      bf16x8 b1 = *(const bf16x8*)&Ks[cur][(ct*16 + lq)*KST2 + 32 + lh*8];
      f32x4 a = (f32x4){0.f,0.f,0.f,0.f};
      a = __builtin_amdgcn_mfma_f32_16x16x32_bf16(qf0, b0, a, 0, 0, 0);
      a = __builtin_amdgcn_mfma_f32_16x16x32_bf16(qf1, b1, a, 0, 0, 0);
      #pragma unroll
      for (int r = 0; r < 4; ++r){
        float e = __expf(a[r] * SCALEF);
        unsigned short eb = f2bf_trunc(e);
        int rrow = lh*4 + r, col = ct*16 + lq;
        Es[w][rrow*EST + col] = eb;
        float ev = bf2f(eb);
        int grow = w*16 + rrow;
        if (!diag || col < grow) dacc[r] += ev;
        if (diag && col == grow) dsh[w][rrow] = ev;
      }
    }
    #pragma unroll
    for (int it = 0; it < 2; ++it){
      int row = it*8 + (l >> 3), eo = (l & 7)*8;
      *(int4*)(Et + row*64 + eo) = *(const int4*)&Es[w][row*EST + eo];
    }
    if (bj < bi){
      *(int4*)&Ks[cur^1][srow*KST2 + sc]     = nk0;
      *(int4*)&Ks[cur^1][srow*KST2 + sc + 8] = nk1;
    }
    __syncthreads();
  }
  #pragma unroll
  for (int r = 0; r < 4; ++r){
    float d = dacc[r];
    #pragma unroll
    for (int mm = 1; mm < 16; mm <<= 1) d += __shfl_xor(d, mm);
    float dE = dsh[w][lh*4 + r];
    float den = fmaf(EPSF, d + dE, d);
    float rv = 1.0f / den;
    if (lq == 0)
      rinvg[(size_t)bh*S_ + bi*64 + w*16 + lh*4 + r] = rv;
  }
}

// ---------------- 4a': per-block unit-lower-triangular inverse (R17).
__global__ __launch_bounds__(64)
void k_dinv(const unsigned short* __restrict__ Eg,
            const float* __restrict__ rinvg,
            unsigned short* __restrict__ Dg){
  __shared__ float As[64*65];
  const int bh = blockIdx.x >> 5, bi = blockIdx.x & 31;
  const unsigned short* Et =
      Eg + ((size_t)bh*528 + (size_t)(bi*(bi+1)/2) + bi)*4096;
  const int c = threadIdx.x;
  for (int r = 0; r < 64; ++r){
    float rv = rinvg[(size_t)bh*S_ + bi*64 + r];
    float e = bf2f(Et[(r>>4)*1024 + (r&15)*64 + c]);
    As[r*65 + c] = (c < r) ? e * rv : 0.f;
  }
  __syncthreads();
  float X[64];
  #pragma unroll
  for (int r = 0; r < 64; ++r){
    float acc = (r == c) ? 1.f : 0.f;
    #pragma unroll
    for (int k = 0; k < r; ++k)
      acc = fmaf(As[r*65 + k], X[k], acc);
    X[r] = acc;
  }
  unsigned short* dt = Dg + (size_t)blockIdx.x * 4096;
  #pragma unroll
  for (int r = 0; r < 64; ++r)
    dt[(r>>4)*1024 + (r&15)*64 + c] = f2bf(X[r]);
}

// ---------------- 4b: striped recurrence v4 — 8 stripes/head (256 WGs, R17).
__global__ __launch_bounds__(512)
__attribute__((amdgpu_waves_per_eu(2, 2)))
void k_recur3(const unsigned short* __restrict__ Eg,
              const unsigned short* __restrict__ Dg,
              const float* __restrict__ rinvg,
              float* __restrict__ c_c,
              float* __restrict__ c_g){
  __shared__ float Pa[256];     // owned block o at Pa[o*64+row]
  __shared__ float rso[256];
  __shared__ float csl[2][64];
  __shared__ float bb[64];
  const int bh = blockIdx.x & 31, s = blockIdx.x >> 5;
  const unsigned short* Eh = Eg + (size_t)bh * 528 * 4096;
  const int tid = threadIdx.x, w = tid >> 6, l = tid & 63;
  const int lq = l & 15, lh = l >> 4;

  if (tid < 256){
    Pa[tid] = 0.f;
    rso[tid] = rinvg[(size_t)bh*S_ + (s + 8*(tid >> 6))*64 + l];
  }
  __syncthreads();

  bf16x8 dv0[4], dv1[4];        // wave0: Dinv tile of next owned block
  if (w == 0){
    const unsigned short* dt = Dg + (size_t)(bh*32 + s)*4096;
    #pragma unroll
    for (int q = 0; q < 4; ++q){
      dv0[q] = *(const bf16x8*)(dt + q*1024 + lq*64 + lh*8);
      dv1[q] = *(const bf16x8*)(dt + q*1024 + lq*64 + 32 + lh*8);
    }
  }

  bf16x8 dA0[3], dA1[3], dB0[3], dB1[3];   // deferred staging ping-pong
  bf16x8 ug0, ug1;                          // urgent tile regs (waves 1-4)
  const int lastc = s + 24;

  auto load_def = [&](int BJ, bf16x8 (&D0)[3], bf16x8 (&D1)[3]){
    int o0 = (BJ >= s) ? (((BJ - s) >> 3) + 1) : 0;
    int ex = (((BJ + 1) & 7) == s) ? 1 : 0;
    int nd = (4 - o0 - ex) * 4;
    if (w >= 1){
      #pragma unroll
      for (int k = 0; k < 3; ++k){
        int t = (w - 1) + k*7;
        if (t < nd){
          int ob = o0 + ex + (t >> 2);
          int bi = s + 8*ob;
          const unsigned short* tp =
              Eh + ((size_t)(bi*(bi+1)/2) + BJ)*4096 + (size_t)(t & 3)*1024;
          D0[k] = *(const bf16x8*)(tp + lq*64 + lh*8);
          D1[k] = *(const bf16x8*)(tp + lq*64 + 32 + lh*8);
        }
      }
      if (ex && w <= 4){
        int bi = BJ + 1;
        const unsigned short* tp =
            Eh + ((size_t)(bi*(bi+1)/2) + BJ)*4096 + (size_t)(w-1)*1024;
        ug0 = *(const bf16x8*)(tp + lq*64 + lh*8);
        ug1 = *(const bf16x8*)(tp + lq*64 + 32 + lh*8);
      }
    }
  };

  auto fold_def = [&](int BJP, bf16x8 (&D0)[3], bf16x8 (&D1)[3], int buf){
    int o0 = (BJP >= s) ? (((BJP - s) >> 3) + 1) : 0;
    int ex = (((BJP + 1) & 7) == s) ? 1 : 0;
    int nd = (4 - o0 - ex) * 4;
    if (w >= 1 && nd > 0){
      bf16x8 dc0 = (bf16x8){0,0,0,0,0,0,0,0};
      bf16x8 dc1 = (bf16x8){0,0,0,0,0,0,0,0};
      if (lq == 0){
        #pragma unroll
        for (int e = 0; e < 8; ++e){
          dc0[e] = (short)f2bf(csl[buf][lh*8 + e]);
          dc1[e] = (short)f2bf(csl[buf][32 + lh*8 + e]);
        }
      }
      #pragma unroll
      for (int k = 0; k < 3; ++k){
        int t = (w - 1) + k*7;
        if (t < nd){
          f32x4 o = (f32x4){0.f,0.f,0.f,0.f};
          o = __builtin_amdgcn_mfma_f32_16x16x32_bf16(D0[k], dc0, o, 0, 0, 0);
          o = __builtin_amdgcn_mfma_f32_16x16x32_bf16(D1[k], dc1, o, 0, 0, 0);
          if (lq == 0){
            int ob = o0 + ex + (t >> 2);
            float* base = Pa + ob*64 + (t & 3)*16 + lh*4;
            float4 v = *(float4*)base;
            v.x += o[0]; v.y += o[1]; v.z += o[2]; v.w += o[3];
            *(float4*)base = v;
          }
        }
      }
    }
  };

  auto iter = [&](int BJ, bf16x8 (&DL0)[3], bf16x8 (&DL1)[3],
                          bf16x8 (&DF0)[3], bf16x8 (&DF1)[3]){
    const int cur = BJ & 1;
    load_def(BJ, DL0, DL1);
    const int ex = (((BJ + 1) & 7) == s) ? 1 : 0;
    if (w == 0){
      if ((BJ & 7) == s){
        // matvec solve: c_blk = Dinv @ (rinv .* Pa), b0 := 1 at global row 0
        const int o = (BJ - s) >> 3;
        float bval = rso[o*64 + l] * Pa[o*64 + l];
        if (BJ == 0 && l == 0) bval = 1.0f;
        bb[l] = bval;
        bf16x8 uc0 = (bf16x8){0,0,0,0,0,0,0,0};
        bf16x8 uc1 = (bf16x8){0,0,0,0,0,0,0,0};
        if (lq == 0){
          #pragma unroll
          for (int e = 0; e < 8; ++e){
            uc0[e] = (short)f2bf(bb[lh*8 + e]);
            uc1[e] = (short)f2bf(bb[32 + lh*8 + e]);
          }
        }
        #pragma unroll
        for (int q = 0; q < 4; ++q){
          f32x4 o4 = (f32x4){0.f,0.f,0.f,0.f};
          o4 = __builtin_amdgcn_mfma_f32_16x16x32_bf16(dv0[q], uc0, o4, 0, 0, 0);
          o4 = __builtin_amdgcn_mfma_f32_16x16x32_bf16(dv1[q], uc1, o4, 0, 0, 0);
          if (lq == 0){
            #pragma unroll
            for (int r = 0; r < 4; ++r)
              csl[cur][q*16 + lh*4 + r] = o4[r];
          }
        }
        float cval = csl[cur][l];
        __hip_atomic_store((unsigned*)(c_c + (size_t)bh*S_ + BJ*64 + l),
                           __float_as_uint(cval),
                           __ATOMIC_RELAXED, __HIP_MEMORY_SCOPE_AGENT);
        c_g[((size_t)(bh >> 4)*S_ + (BJ*64 + l))*16 + (bh & 15)] = cval;
        int bn = BJ + 8;            // prefetch next owned Dinv tile
        if (bn <= lastc){
          const unsigned short* dt = Dg + (size_t)(bh*32 + bn)*4096;
          #pragma unroll
          for (int q = 0; q < 4; ++q){
            dv0[q] = *(const bf16x8*)(dt + q*1024 + lq*64 + lh*8);
            dv1[q] = *(const bf16x8*)(dt + q*1024 + lq*64 + 32 + lh*8);
          }
        }
      } else {
        const unsigned* pp = (const unsigned*)(c_c + (size_t)bh*S_ + BJ*64 + l);
        unsigned v = __hip_atomic_load(pp, __ATOMIC_RELAXED,
                                       __HIP_MEMORY_SCOPE_AGENT);
        while (!__all(v != 0u)){
          __builtin_amdgcn_s_sleep(2);
          v = __hip_atomic_load(pp, __ATOMIC_RELAXED,
                                __HIP_MEMORY_SCOPE_AGENT);
        }
        csl[cur][l] = __uint_as_float(v);
      }
    } else if (BJ >= 1){
      fold_def(BJ - 1, DF0, DF1, cur ^ 1);
    }
    __syncthreads();
    // phase B: urgent fold (col BJ -> block BJ+1), waves 1-4
    if (ex && w >= 1 && w <= 4){
      bf16x8 uc0 = (bf16x8){0,0,0,0,0,0,0,0};
      bf16x8 uc1 = (bf16x8){0,0,0,0,0,0,0,0};
      if (lq == 0){
        #pragma unroll
        for (int e = 0; e < 8; ++e){
          uc0[e] = (short)f2bf(csl[cur][lh*8 + e]);
          uc1[e] = (short)f2bf(csl[cur][32 + lh*8 + e]);
        }
      }
      f32x4 o = (f32x4){0.f,0.f,0.f,0.f};
      o = __builtin_amdgcn_mfma_f32_16x16x32_bf16(ug0, uc0, o, 0, 0, 0);
      o = __builtin_amdgcn_mfma_f32_16x16x32_bf16(ug1, uc1, o, 0, 0, 0);
      if (lq == 0){
        int ou = (BJ + 1 - s) >> 3;
        float* base = Pa + ou*64 + (w-1)*16 + lh*4;
        float4 v = *(float4*)base;
        v.x += o[0]; v.y += o[1]; v.z += o[2]; v.w += o[3];
        *(float4*)base = v;
      }
    }
    __syncthreads();
  };

  for (int bj = 0; bj <= lastc; bj += 2){
    iter(bj,     dA0, dA1, dB0, dB1);
    if (bj + 1 <= lastc)
      iter(bj+1, dB0, dB1, dA0, dA1);
  }
}

// ---------------- 5: out[b,s,n] = bd[n] + sum_h c[b,s,h] * U[b,h,n]
__global__ void k_out(const float* __restrict__ c_g, const float* __restrict__ U,
                      const float* __restrict__ bd, float* __restrict__ out){
  int bs = blockIdx.x; int b = bs >> 11;
  __shared__ float ch[16];
  if (threadIdx.x < 16) ch[threadIdx.x] = c_g[(size_t)bs*16 + threadIdx.x];
  __syncthreads();
  int n = threadIdx.x * 4;
  float4 acc = *(const float4*)(bd + n);
  #pragma unroll
  for (int h = 0; h < 16; ++h){
    float cc = ch[h];
    float4 u = *(const float4*)(U + ((size_t)(b*16 + h))*1024 + n);
    acc.x = fmaf(cc, u.x, acc.x); acc.y = fmaf(cc, u.y, acc.y);
    acc.z = fmaf(cc, u.z, acc.z); acc.w = fmaf(cc, u.w, acc.w);
  }
  *(float4*)(out + (size_t)bs*1024 + n) = acc;
}

extern "C" void kernel_launch(void* const* d_in, const int* in_sizes, int n_in,
                              void* d_out, int out_size, void* d_ws, size_t ws_size,
                              hipStream_t stream) {
  const float* hs   = (const float*)d_in[0];   // [2][2048][1024]
  const int*   pos  = (const int*)d_in[1];     // [2048]
  const float* Wqkv = (const float*)d_in[2];   // [1024][3072]
  const float* bqkv = (const float*)d_in[3];   // [3072]
  const float* Wd   = (const float*)d_in[4];   // [1024][1024]
  const float* bd   = (const float*)d_in[5];   // [1024]
  float* out = (float*)d_out;

  // workspace layout. Dg overlays Ab (dead after k_gemm_qk).
  char* ws = (char*)d_ws;
  unsigned short* Ab = (unsigned short*)(ws);                       // 8 MB
  unsigned short* Dg = (unsigned short*)(ws);                       // 8 MB (reuse)
  unsigned short* WT = (unsigned short*)(ws + (8u<<20));            // 4 MB
  unsigned short* Qb = (unsigned short*)(ws + (12u<<20));           // 8 MB
  unsigned short* Kb = (unsigned short*)(ws + (20u<<20));           // 8 MB
  float* c_g  = (float*)(ws + (28u<<20) + 0x10000);                 // 256 KB
  float* U    = (float*)(ws + (28u<<20) + 0x50000);                 // 128 KB
  float* rinvg= (float*)(ws + (28u<<20) + 0x80000);                 // 256 KB
  float* c_c  = (float*)(ws + (28u<<20) + 0xC0000);                 // 256 KB
  unsigned short* Eg = (unsigned short*)(ws + (29u<<20));           // 132 MB

  k_prep   <<<6240, 256, 0, stream>>>(hs, Wqkv, bqkv, Wd, Ab, WT, U, c_c);
  k_gemm_qk<<<dim3(16, 32), 256, 0, stream>>>(Ab, WT, bqkv, pos, Qb, Kb);
  k_scores <<<1024, 256, 0, stream>>>(Qb, Kb, Eg, rinvg);
  k_dinv   <<<1024, 64, 0, stream>>>(Eg, rinvg, Dg);
  k_recur3 <<<256, 512, 0, stream>>>(Eg, Dg, rinvg, c_c, c_g);
  k_out    <<<4096, 256, 0, stream>>>(c_g, U, bd, out);
}

// Round 21
// 169.001 us; speedup vs baseline: 1.3994x; 1.0511x over previous
//
#include <hip/hip_runtime.h>

// Problem constants (B=2, S=2048, HIDDEN=1024, HEADS=16, HEAD_DIM=64, ROT=16)
#define S_ 2048
#define EPSF 1e-8f
#define SCALEF 0.125f

typedef short bf16x8 __attribute__((ext_vector_type(8)));
typedef float f32x4 __attribute__((ext_vector_type(4)));

__device__ __forceinline__ unsigned short f2bf(float f){
  unsigned int u = __float_as_uint(f);
  u = (u + 0x7fffu + ((u >> 16) & 1u)) >> 16;
  return (unsigned short)u;
}
__device__ __forceinline__ float bf2f(unsigned short h){
  return __uint_as_float(((unsigned int)h) << 16);
}
__device__ __forceinline__ unsigned short f2bf_trunc(float f){
  return (unsigned short)(__float_as_uint(f) >> 16);
}

#define GLD16(g, l) __builtin_amdgcn_global_load_lds( \
    (const __attribute__((address_space(1))) unsigned int*)(g), \
    (__attribute__((address_space(3))) unsigned int*)(l), 16, 0, 0)

// ---------------- 1: merged prep. Role order puts the LATENCY-TAIL blocks
// (v0+U: two serial dot-loops, ~25us) FIRST so they start at t=0 and hide
// under the 6k cheap convert blocks (R19: they were dispatched last -> 48us
// kernel tail at 14% occupancy).
__global__ void k_prep(const float* __restrict__ hs, const float* __restrict__ Wqkv,
                       const float* __restrict__ bqkv, const float* __restrict__ Wd,
                       unsigned short* __restrict__ Ab,
                       unsigned short* __restrict__ WT,
                       float* __restrict__ U,
                       float* __restrict__ c_c){
  __shared__ float t[32][33];     // conv_wt path
  __shared__ float red[4][64];    // v0 path
  __shared__ float vsh[64];
  int bid = blockIdx.x;
  if (bid < 32){
    // v0 = hs[b,0,:] @ Wqkv[:,2048+h*64+:] + b; then U = v0 @ Wd rows
    int bh = bid; int b = bh >> 4, h = bh & 15;
    int d = threadIdx.x & 63, kc = threadIdx.x >> 6;
    const float* x = hs + (size_t)b * S_ * 1024;
    int col = 2048 + h*64 + d;
    float acc = 0.f;
    #pragma unroll 16
    for (int k = kc*256; k < kc*256 + 256; ++k)
      acc = fmaf(x[k], Wqkv[(size_t)k*3072 + col], acc);
    red[kc][d] = acc;
    __syncthreads();
    if (kc == 0)
      vsh[d] = red[0][d] + red[1][d] + red[2][d] + red[3][d] + bqkv[col];
    __syncthreads();
    for (int n = threadIdx.x; n < 1024; n += 256){
      float a2 = 0.f;
      #pragma unroll 16
      for (int dd = 0; dd < 64; ++dd)
        a2 = fmaf(vsh[dd], Wd[(size_t)(h*64 + dd)*1024 + n], a2);
      U[(size_t)bh*1024 + n] = a2;
    }
  } else if (bid < 96){
    // zero c_c: 64 blocks x 4KB = 256KB
    int q = bid - 32;
    float4 z = (float4){0.f,0.f,0.f,0.f};
    *(float4*)(c_c + (size_t)q*1024 + threadIdx.x*4) = z;
  } else if (bid < 4192){
    int i = ((bid - 96) * 256 + threadIdx.x) * 4;
    float4 v = *(const float4*)(hs + i);
    ushort4 o; o.x=f2bf(v.x); o.y=f2bf(v.y); o.z=f2bf(v.z); o.w=f2bf(v.w);
    *(ushort4*)(Ab + i) = o;
  } else {
    int q = bid - 4192;
    int nt = q & 63, kt = q >> 6;
    int tx = threadIdx.x & 31, ty = threadIdx.x >> 5;   // 32 x 8
    #pragma unroll
    for (int r = 0; r < 32; r += 8)
      t[ty + r][tx] = Wqkv[(size_t)(kt*32 + ty + r)*3072 + nt*32 + tx];
    __syncthreads();
    #pragma unroll
    for (int r = 0; r < 32; r += 8)
      WT[(size_t)(nt*32 + ty + r)*1024 + kt*32 + tx] = f2bf(t[tx][ty + r]);
  }
}

// ---------------- 2: QK projection GEMM + fused RoPE epilogue (m97 staging).
#define BK 32
__launch_bounds__(256)
__global__ void k_gemm_qk(const unsigned short* __restrict__ Ab,
                          const unsigned short* __restrict__ WT,
                          const float* __restrict__ bqkv,
                          const int* __restrict__ pos_ids,
                          unsigned short* __restrict__ Qb,
                          unsigned short* __restrict__ Kb){
  __shared__ unsigned short At[128*BK];   // 8 KB, linear
  __shared__ unsigned short Bt[128*BK];   // 8 KB, linear
  const int m0 = blockIdx.y * 128, n0 = blockIdx.x * 128;
  const int w = threadIdx.x >> 6, l = threadIdx.x & 63;
  const int wr = w >> 1, wc = w & 1;
  const int lq = l & 15, lh = l >> 4;
  f32x4 acc[4][4];
  #pragma unroll
  for (int i = 0; i < 4; ++i)
    #pragma unroll
    for (int j = 0; j < 4; ++j) acc[i][j] = (f32x4){0.f,0.f,0.f,0.f};

  const int srow = l >> 2;
  const int scol = (l & 3) * 8;

  for (int kt = 0; kt < 1024; kt += BK){
    GLD16(Ab + (size_t)(m0 + w*32 +      srow)*1024 + kt + scol, &At[(w*32)*BK]);
    GLD16(Ab + (size_t)(m0 + w*32 + 16 + srow)*1024 + kt + scol, &At[(w*32+16)*BK]);
    GLD16(WT + (size_t)(n0 + w*32 +      srow)*1024 + kt + scol, &Bt[(w*32)*BK]);
    GLD16(WT + (size_t)(n0 + w*32 + 16 + srow)*1024 + kt + scol, &Bt[(w*32+16)*BK]);
    __syncthreads();
    bf16x8 af[4], bf[4];
    #pragma unroll
    for (int i = 0; i < 4; ++i)
      af[i] = *(const bf16x8*)&At[(wr*64 + i*16 + lq)*BK + lh*8];
    #pragma unroll
    for (int j = 0; j < 4; ++j)
      bf[j] = *(const bf16x8*)&Bt[(wc*64 + j*16 + lq)*BK + lh*8];
    #pragma unroll
    for (int i = 0; i < 4; ++i)
      #pragma unroll
      for (int j = 0; j < 4; ++j)
        acc[i][j] = __builtin_amdgcn_mfma_f32_16x16x32_bf16(af[i], bf[j], acc[i][j], 0, 0, 0);
    __syncthreads();
  }
  #pragma unroll
  for (int i = 0; i < 4; ++i){
    #pragma unroll
    for (int j = 0; j < 4; ++j){
      #pragma unroll
      for (int r = 0; r < 4; ++r){
        int m = m0 + wr*64 + i*16 + (l>>4)*4 + r;
        int n = n0 + wc*64 + j*16 + (l&15);
        float v = acc[i][j][r] + bqkv[n];
        if (j == 0){   // rotary dims d = lq < 16
          float partner = __shfl_xor(v, 8);
          int s = m & 2047;
          float pos = (float)pos_ids[s];
          float fr = exp2f(-1.6609640474436813f * (float)(l & 7));
          float th = pos * fr;
          float sn = __sinf(th), cn = __cosf(th);
          v = ((l & 8) == 0) ? (v*cn - partner*sn) : (v*cn + partner*sn);
        }
        int b = m >> 11, s2 = m & 2047;
        int tsel = n >> 10; int nq = n & 1023;
        int h = nq >> 6, d = nq & 63;
        unsigned short* dst = tsel ? Kb : Qb;
        dst[((size_t)(b*16 + h)*S_ + s2)*64 + d] = f2bf(v);
      }
    }
  }
}

// ---------------- 4a: full-chip E + rinv precompute (R19: balanced bi).
#define KST2 66
#define EST 68
__launch_bounds__(256, 4)
__global__ void k_scores(const unsigned short* __restrict__ Qb,
                         const unsigned short* __restrict__ Kb,
                         unsigned short* __restrict__ Eg,
                         float* __restrict__ rinvg){
  __shared__ unsigned short Ks[2][64*KST2];
  __shared__ unsigned short Es[4][16*EST];
  __shared__ float dsh[4][16];
  const int q = blockIdx.x >> 5, bh = blockIdx.x & 31;
  const int qm = q & 7, qk = q >> 3;
  const int bi = (qk == 0) ? qm : (qk == 1) ? (15 - qm)
               : (qk == 2) ? (16 + qm) : (31 - qm);
  const unsigned short* Qh = Qb + (size_t)bh * S_ * 64;
  const unsigned short* Kh = Kb + (size_t)bh * S_ * 64;
  const int tid = threadIdx.x, w = tid >> 6, l = tid & 63;
  const int lq = l & 15, lh = l >> 4;
  const unsigned short* qp = Qh + (size_t)(bi*64 + w*16 + lq)*64 + lh*8;
  bf16x8 qf0 = *(const bf16x8*)(qp);
  bf16x8 qf1 = *(const bf16x8*)(qp + 32);
  float dacc[4] = {0.f,0.f,0.f,0.f};
  unsigned short* Etile0 = Eg + ((size_t)bh*528 + (size_t)(bi*(bi+1)/2))*4096;
  const int srow = tid >> 2, sc = (tid & 3)*16;

  {
    const unsigned short* src = Kh + (size_t)srow*64 + sc;
    *(int4*)&Ks[0][srow*KST2 + sc]     = *(const int4*)(src);
    *(int4*)&Ks[0][srow*KST2 + sc + 8] = *(const int4*)(src + 8);
  }
  __syncthreads();

  for (int bj = 0; bj <= bi; ++bj){
    const int cur = bj & 1;
    int4 nk0, nk1;
    if (bj < bi){
      const unsigned short* src = Kh + (size_t)((bj+1)*64 + srow)*64 + sc;
      nk0 = *(const int4*)(src);
      nk1 = *(const int4*)(src + 8);
    }
    unsigned short* Et = Etile0 + (size_t)bj*4096 + w*1024;
    const bool diag = (bj == bi);
    #pragma unroll
    for (int ct = 0; ct < 4; ++ct){
      bf16x8 b0 = *(const bf16x8*)&Ks[cur][(ct*16 + lq)*KST2 + lh*8];
      bf16x8 b1 = *(const bf16x8*)&Ks[cur][(ct*16 + lq)*KST2 + 32 + lh*8];
      f32x4 a = (f32x4){0.f,0.f,0.f,0.f};
      a = __builtin_amdgcn_mfma_f32_16x16x32_bf16(qf0, b0, a, 0, 0, 0);
      a = __builtin_amdgcn_mfma_f32_16x16x32_bf16(qf1, b1, a, 0, 0, 0);
      #pragma unroll
      for (int r = 0; r < 4; ++r){
        float e = __expf(a[r] * SCALEF);
        unsigned short eb = f2bf_trunc(e);
        int rrow = lh*4 + r, col = ct*16 + lq;
        Es[w][rrow*EST + col] = eb;
        float ev = bf2f(eb);
        int grow = w*16 + rrow;
        if (!diag || col < grow) dacc[r] += ev;
        if (diag && col == grow) dsh[w][rrow] = ev;
      }
    }
    #pragma unroll
    for (int it = 0; it < 2; ++it){
      int row = it*8 + (l >> 3), eo = (l & 7)*8;
      *(int4*)(Et + row*64 + eo) = *(const int4*)&Es[w][row*EST + eo];
    }
    if (bj < bi){
      *(int4*)&Ks[cur^1][srow*KST2 + sc]     = nk0;
      *(int4*)&Ks[cur^1][srow*KST2 + sc + 8] = nk1;
    }
    __syncthreads();
  }
  #pragma unroll
  for (int r = 0; r < 4; ++r){
    float d = dacc[r];
    #pragma unroll
    for (int mm = 1; mm < 16; mm <<= 1) d += __shfl_xor(d, mm);
    float dE = dsh[w][lh*4 + r];
    float den = fmaf(EPSF, d + dE, d);
    float rv = 1.0f / den;
    if (lq == 0)
      rinvg[(size_t)bh*S_ + bi*64 + w*16 + lh*4 + r] = rv;
  }
}

// ---------------- 4a': per-block unit-lower-triangular inverse (R17).
__global__ __launch_bounds__(64)
void k_dinv(const unsigned short* __restrict__ Eg,
            const float* __restrict__ rinvg,
            unsigned short* __restrict__ Dg){
  __shared__ float As[64*65];
  const int bh = blockIdx.x >> 5, bi = blockIdx.x & 31;
  const unsigned short* Et =
      Eg + ((size_t)bh*528 + (size_t)(bi*(bi+1)/2) + bi)*4096;
  const int c = threadIdx.x;
  for (int r = 0; r < 64; ++r){
    float rv = rinvg[(size_t)bh*S_ + bi*64 + r];
    float e = bf2f(Et[(r>>4)*1024 + (r&15)*64 + c]);
    As[r*65 + c] = (c < r) ? e * rv : 0.f;
  }
  __syncthreads();
  float X[64];
  #pragma unroll
  for (int r = 0; r < 64; ++r){
    float acc = (r == c) ? 1.f : 0.f;
    #pragma unroll
    for (int k = 0; k < r; ++k)
      acc = fmaf(As[r*65 + k], X[k], acc);
    X[r] = acc;
  }
  unsigned short* dt = Dg + (size_t)blockIdx.x * 4096;
  #pragma unroll
  for (int r = 0; r < 64; ++r)
    dt[(r>>4)*1024 + (r&15)*64 + c] = f2bf(X[r]);
}

// ---------------- 4b: striped recurrence v4 — 8 stripes/head (256 WGs, R17).
__global__ __launch_bounds__(512)
__attribute__((amdgpu_waves_per_eu(2, 2)))
void k_recur3(const unsigned short* __restrict__ Eg,
              const unsigned short* __restrict__ Dg,
              const float* __restrict__ rinvg,
              float* __restrict__ c_c,
              float* __restrict__ c_g){
  __shared__ float Pa[256];     // owned block o at Pa[o*64+row]
  __shared__ float rso[256];
  __shared__ float csl[2][64];
  __shared__ float bb[64];
  const int bh = blockIdx.x & 31, s = blockIdx.x >> 5;
  const unsigned short* Eh = Eg + (size_t)bh * 528 * 4096;
  const int tid = threadIdx.x, w = tid >> 6, l = tid & 63;
  const int lq = l & 15, lh = l >> 4;

  if (tid < 256){
    Pa[tid] = 0.f;
    rso[tid] = rinvg[(size_t)bh*S_ + (s + 8*(tid >> 6))*64 + l];
  }
  __syncthreads();

  bf16x8 dv0[4], dv1[4];        // wave0: Dinv tile of next owned block
  if (w == 0){
    const unsigned short* dt = Dg + (size_t)(bh*32 + s)*4096;
    #pragma unroll
    for (int q = 0; q < 4; ++q){
      dv0[q] = *(const bf16x8*)(dt + q*1024 + lq*64 + lh*8);
      dv1[q] = *(const bf16x8*)(dt + q*1024 + lq*64 + 32 + lh*8);
    }
  }

  bf16x8 dA0[3], dA1[3], dB0[3], dB1[3];   // deferred staging ping-pong
  bf16x8 ug0, ug1;                          // urgent tile regs (waves 1-4)
  const int lastc = s + 24;

  auto load_def = [&](int BJ, bf16x8 (&D0)[3], bf16x8 (&D1)[3]){
    int o0 = (BJ >= s) ? (((BJ - s) >> 3) + 1) : 0;
    int ex = (((BJ + 1) & 7) == s) ? 1 : 0;
    int nd = (4 - o0 - ex) * 4;
    if (w >= 1){
      #pragma unroll
      for (int k = 0; k < 3; ++k){
        int t = (w - 1) + k*7;
        if (t < nd){
          int ob = o0 + ex + (t >> 2);
          int bi = s + 8*ob;
          const unsigned short* tp =
              Eh + ((size_t)(bi*(bi+1)/2) + BJ)*4096 + (size_t)(t & 3)*1024;
          D0[k] = *(const bf16x8*)(tp + lq*64 + lh*8);
          D1[k] = *(const bf16x8*)(tp + lq*64 + 32 + lh*8);
        }
      }
      if (ex && w <= 4){
        int bi = BJ + 1;
        const unsigned short* tp =
            Eh + ((size_t)(bi*(bi+1)/2) + BJ)*4096 + (size_t)(w-1)*1024;
        ug0 = *(const bf16x8*)(tp + lq*64 + lh*8);
        ug1 = *(const bf16x8*)(tp + lq*64 + 32 + lh*8);
      }
    }
  };

  auto fold_def = [&](int BJP, bf16x8 (&D0)[3], bf16x8 (&D1)[3], int buf){
    int o0 = (BJP >= s) ? (((BJP - s) >> 3) + 1) : 0;
    int ex = (((BJP + 1) & 7) == s) ? 1 : 0;
    int nd = (4 - o0 - ex) * 4;
    if (w >= 1 && nd > 0){
      bf16x8 dc0 = (bf16x8){0,0,0,0,0,0,0,0};
      bf16x8 dc1 = (bf16x8){0,0,0,0,0,0,0,0};
      if (lq == 0){
        #pragma unroll
        for (int e = 0; e < 8; ++e){
          dc0[e] = (short)f2bf(csl[buf][lh*8 + e]);
          dc1[e] = (short)f2bf(csl[buf][32 + lh*8 + e]);
        }
      }
      #pragma unroll
      for (int k = 0; k < 3; ++k){
        int t = (w - 1) + k*7;
        if (t < nd){
          f32x4 o = (f32x4){0.f,0.f,0.f,0.f};
          o = __builtin_amdgcn_mfma_f32_16x16x32_bf16(D0[k], dc0, o, 0, 0, 0);
          o = __builtin_amdgcn_mfma_f32_16x16x32_bf16(D1[k], dc1, o, 0, 0, 0);
          if (lq == 0){
            int ob = o0 + ex + (t >> 2);
            float* base = Pa + ob*64 + (t & 3)*16 + lh*4;
            float4 v = *(float4*)base;
            v.x += o[0]; v.y += o[1]; v.z += o[2]; v.w += o[3];
            *(float4*)base = v;
          }
        }
      }
    }
  };

  auto iter = [&](int BJ, bf16x8 (&DL0)[3], bf16x8 (&DL1)[3],
                          bf16x8 (&DF0)[3], bf16x8 (&DF1)[3]){
    const int cur = BJ & 1;
    load_def(BJ, DL0, DL1);
    const int ex = (((BJ + 1) & 7) == s) ? 1 : 0;
    if (w == 0){
      if ((BJ & 7) == s){
        // matvec solve: c_blk = Dinv @ (rinv .* Pa), b0 := 1 at global row 0
        const int o = (BJ - s) >> 3;
        float bval = rso[o*64 + l] * Pa[o*64 + l];
        if (BJ == 0 && l == 0) bval = 1.0f;
        bb[l] = bval;
        bf16x8 uc0 = (bf16x8){0,0,0,0,0,0,0,0};
        bf16x8 uc1 = (bf16x8){0,0,0,0,0,0,0,0};
        if (lq == 0){
          #pragma unroll
          for (int e = 0; e < 8; ++e){
            uc0[e] = (short)f2bf(bb[lh*8 + e]);
            uc1[e] = (short)f2bf(bb[32 + lh*8 + e]);
          }
        }
        #pragma unroll
        for (int q = 0; q < 4; ++q){
          f32x4 o4 = (f32x4){0.f,0.f,0.f,0.f};
          o4 = __builtin_amdgcn_mfma_f32_16x16x32_bf16(dv0[q], uc0, o4, 0, 0, 0);
          o4 = __builtin_amdgcn_mfma_f32_16x16x32_bf16(dv1[q], uc1, o4, 0, 0, 0);
          if (lq == 0){
            #pragma unroll
            for (int r = 0; r < 4; ++r)
              csl[cur][q*16 + lh*4 + r] = o4[r];
          }
        }
        float cval = csl[cur][l];
        __hip_atomic_store((unsigned*)(c_c + (size_t)bh*S_ + BJ*64 + l),
                           __float_as_uint(cval),
                           __ATOMIC_RELAXED, __HIP_MEMORY_SCOPE_AGENT);
        c_g[((size_t)(bh >> 4)*S_ + (BJ*64 + l))*16 + (bh & 15)] = cval;
        int bn = BJ + 8;            // prefetch next owned Dinv tile
        if (bn <= lastc){
          const unsigned short* dt = Dg + (size_t)(bh*32 + bn)*4096;
          #pragma unroll
          for (int q = 0; q < 4; ++q){
            dv0[q] = *(const bf16x8*)(dt + q*1024 + lq*64 + lh*8);
            dv1[q] = *(const bf16x8*)(dt + q*1024 + lq*64 + 32 + lh*8);
          }
        }
      } else {
        const unsigned* pp = (const unsigned*)(c_c + (size_t)bh*S_ + BJ*64 + l);
        unsigned v = __hip_atomic_load(pp, __ATOMIC_RELAXED,
                                       __HIP_MEMORY_SCOPE_AGENT);
        while (!__all(v != 0u)){
          __builtin_amdgcn_s_sleep(2);
          v = __hip_atomic_load(pp, __ATOMIC_RELAXED,
                                __HIP_MEMORY_SCOPE_AGENT);
        }
        csl[cur][l] = __uint_as_float(v);
      }
    } else if (BJ >= 1){
      fold_def(BJ - 1, DF0, DF1, cur ^ 1);
    }
    __syncthreads();
    // phase B: urgent fold (col BJ -> block BJ+1), waves 1-4
    if (ex && w >= 1 && w <= 4){
      bf16x8 uc0 = (bf16x8){0,0,0,0,0,0,0,0};
      bf16x8 uc1 = (bf16x8){0,0,0,0,0,0,0,0};
      if (lq == 0){
        #pragma unroll
        for (int e = 0; e < 8; ++e){
          uc0[e] = (short)f2bf(csl[cur][lh*8 + e]);
          uc1[e] = (short)f2bf(csl[cur][32 + lh*8 + e]);
        }
      }
      f32x4 o = (f32x4){0.f,0.f,0.f,0.f};
      o = __builtin_amdgcn_mfma_f32_16x16x32_bf16(ug0, uc0, o, 0, 0, 0);
      o = __builtin_amdgcn_mfma_f32_16x16x32_bf16(ug1, uc1, o, 0, 0, 0);
      if (lq == 0){
        int ou = (BJ + 1 - s) >> 3;
        float* base = Pa + ou*64 + (w-1)*16 + lh*4;
        float4 v = *(float4*)base;
        v.x += o[0]; v.y += o[1]; v.z += o[2]; v.w += o[3];
        *(float4*)base = v;
      }
    }
    __syncthreads();
  };

  for (int bj = 0; bj <= lastc; bj += 2){
    iter(bj,     dA0, dA1, dB0, dB1);
    if (bj + 1 <= lastc)
      iter(bj+1, dB0, dB1, dA0, dA1);
  }
}

// ---------------- 5: out[b,s,n] = bd[n] + sum_h c[b,s,h] * U[b,h,n]
__global__ void k_out(const float* __restrict__ c_g, const float* __restrict__ U,
                      const float* __restrict__ bd, float* __restrict__ out){
  int bs = blockIdx.x; int b = bs >> 11;
  __shared__ float ch[16];
  if (threadIdx.x < 16) ch[threadIdx.x] = c_g[(size_t)bs*16 + threadIdx.x];
  __syncthreads();
  int n = threadIdx.x * 4;
  float4 acc = *(const float4*)(bd + n);
  #pragma unroll
  for (int h = 0; h < 16; ++h){
    float cc = ch[h];
    float4 u = *(const float4*)(U + ((size_t)(b*16 + h))*1024 + n);
    acc.x = fmaf(cc, u.x, acc.x); acc.y = fmaf(cc, u.y, acc.y);
    acc.z = fmaf(cc, u.z, acc.z); acc.w = fmaf(cc, u.w, acc.w);
  }
  *(float4*)(out + (size_t)bs*1024 + n) = acc;
}

extern "C" void kernel_launch(void* const* d_in, const int* in_sizes, int n_in,
                              void* d_out, int out_size, void* d_ws, size_t ws_size,
                              hipStream_t stream) {
  const float* hs   = (const float*)d_in[0];   // [2][2048][1024]
  const int*   pos  = (const int*)d_in[1];     // [2048]
  const float* Wqkv = (const float*)d_in[2];   // [1024][3072]
  const float* bqkv = (const float*)d_in[3];   // [3072]
  const float* Wd   = (const float*)d_in[4];   // [1024][1024]
  const float* bd   = (const float*)d_in[5];   // [1024]
  float* out = (float*)d_out;

  // workspace layout. Dg overlays Ab (dead after k_gemm_qk).
  char* ws = (char*)d_ws;
  unsigned short* Ab = (unsigned short*)(ws);                       // 8 MB
  unsigned short* Dg = (unsigned short*)(ws);                       // 8 MB (reuse)
  unsigned short* WT = (unsigned short*)(ws + (8u<<20));            // 4 MB
  unsigned short* Qb = (unsigned short*)(ws + (12u<<20));           // 8 MB
  unsigned short* Kb = (unsigned short*)(ws + (20u<<20));           // 8 MB
  float* c_g  = (float*)(ws + (28u<<20) + 0x10000);                 // 256 KB
  float* U    = (float*)(ws + (28u<<20) + 0x50000);                 // 128 KB
  float* rinvg= (float*)(ws + (28u<<20) + 0x80000);                 // 256 KB
  float* c_c  = (float*)(ws + (28u<<20) + 0xC0000);                 // 256 KB
  unsigned short* Eg = (unsigned short*)(ws + (29u<<20));           // 132 MB

  k_prep   <<<6240, 256, 0, stream>>>(hs, Wqkv, bqkv, Wd, Ab, WT, U, c_c);
  k_gemm_qk<<<dim3(16, 32), 256, 0, stream>>>(Ab, WT, bqkv, pos, Qb, Kb);
  k_scores <<<1024, 256, 0, stream>>>(Qb, Kb, Eg, rinvg);
  k_dinv   <<<1024, 64, 0, stream>>>(Eg, rinvg, Dg);
  k_recur3 <<<256, 512, 0, stream>>>(Eg, Dg, rinvg, c_c, c_g);
  k_out    <<<4096, 256, 0, stream>>>(c_g, U, bd, out);
}

// Round 22
// 168.881 us; speedup vs baseline: 1.4003x; 1.0007x over previous
//
#include <hip/hip_runtime.h>

// Problem constants (B=2, S=2048, HIDDEN=1024, HEADS=16, HEAD_DIM=64, ROT=16)
#define S_ 2048
#define EPSF 1e-8f
#define SCALEF 0.125f

typedef short bf16x8 __attribute__((ext_vector_type(8)));
typedef float f32x4 __attribute__((ext_vector_type(4)));

__device__ __forceinline__ unsigned short f2bf(float f){
  unsigned int u = __float_as_uint(f);
  u = (u + 0x7fffu + ((u >> 16) & 1u)) >> 16;
  return (unsigned short)u;
}
__device__ __forceinline__ float bf2f(unsigned short h){
  return __uint_as_float(((unsigned int)h) << 16);
}
__device__ __forceinline__ unsigned short f2bf_trunc(float f){
  return (unsigned short)(__float_as_uint(f) >> 16);
}

#define GLD16(g, l) __builtin_amdgcn_global_load_lds( \
    (const __attribute__((address_space(1))) unsigned int*)(g), \
    (__attribute__((address_space(3))) unsigned int*)(l), 16, 0, 0)

// ---------------- 1: merged prep. Role order puts the LATENCY-TAIL blocks
// (v0+U: two serial dot-loops, ~25us) FIRST so they start at t=0 and hide
// under the 6k cheap convert blocks (R19: they were dispatched last -> 48us
// kernel tail at 14% occupancy).
__global__ void k_prep(const float* __restrict__ hs, const float* __restrict__ Wqkv,
                       const float* __restrict__ bqkv, const float* __restrict__ Wd,
                       unsigned short* __restrict__ Ab,
                       unsigned short* __restrict__ WT,
                       float* __restrict__ U,
                       float* __restrict__ c_c){
  __shared__ float t[32][33];     // conv_wt path
  __shared__ float red[4][64];    // v0 path
  __shared__ float vsh[64];
  int bid = blockIdx.x;
  if (bid < 32){
    // v0 = hs[b,0,:] @ Wqkv[:,2048+h*64+:] + b; then U = v0 @ Wd rows
    int bh = bid; int b = bh >> 4, h = bh & 15;
    int d = threadIdx.x & 63, kc = threadIdx.x >> 6;
    const float* x = hs + (size_t)b * S_ * 1024;
    int col = 2048 + h*64 + d;
    float acc = 0.f;
    #pragma unroll 16
    for (int k = kc*256; k < kc*256 + 256; ++k)
      acc = fmaf(x[k], Wqkv[(size_t)k*3072 + col], acc);
    red[kc][d] = acc;
    __syncthreads();
    if (kc == 0)
      vsh[d] = red[0][d] + red[1][d] + red[2][d] + red[3][d] + bqkv[col];
    __syncthreads();
    for (int n = threadIdx.x; n < 1024; n += 256){
      float a2 = 0.f;
      #pragma unroll 16
      for (int dd = 0; dd < 64; ++dd)
        a2 = fmaf(vsh[dd], Wd[(size_t)(h*64 + dd)*1024 + n], a2);
      U[(size_t)bh*1024 + n] = a2;
    }
  } else if (bid < 96){
    // zero c_c: 64 blocks x 4KB = 256KB
    int q = bid - 32;
    float4 z = (float4){0.f,0.f,0.f,0.f};
    *(float4*)(c_c + (size_t)q*1024 + threadIdx.x*4) = z;
  } else if (bid < 4192){
    int i = ((bid - 96) * 256 + threadIdx.x) * 4;
    float4 v = *(const float4*)(hs + i);
    ushort4 o; o.x=f2bf(v.x); o.y=f2bf(v.y); o.z=f2bf(v.z); o.w=f2bf(v.w);
    *(ushort4*)(Ab + i) = o;
  } else {
    int q = bid - 4192;
    int nt = q & 63, kt = q >> 6;
    int tx = threadIdx.x & 31, ty = threadIdx.x >> 5;   // 32 x 8
    #pragma unroll
    for (int r = 0; r < 32; r += 8)
      t[ty + r][tx] = Wqkv[(size_t)(kt*32 + ty + r)*3072 + nt*32 + tx];
    __syncthreads();
    #pragma unroll
    for (int r = 0; r < 32; r += 8)
      WT[(size_t)(nt*32 + ty + r)*1024 + kt*32 + tx] = f2bf(t[tx][ty + r]);
  }
}

// ---------------- 2: QK projection GEMM + fused RoPE epilogue (m97 staging).
#define BK 32
__launch_bounds__(256)
__global__ void k_gemm_qk(const unsigned short* __restrict__ Ab,
                          const unsigned short* __restrict__ WT,
                          const float* __restrict__ bqkv,
                          const int* __restrict__ pos_ids,
                          unsigned short* __restrict__ Qb,
                          unsigned short* __restrict__ Kb){
  __shared__ unsigned short At[128*BK];   // 8 KB, linear
  __shared__ unsigned short Bt[128*BK];   // 8 KB, linear
  const int m0 = blockIdx.y * 128, n0 = blockIdx.x * 128;
  const int w = threadIdx.x >> 6, l = threadIdx.x & 63;
  const int wr = w >> 1, wc = w & 1;
  const int lq = l & 15, lh = l >> 4;
  f32x4 acc[4][4];
  #pragma unroll
  for (int i = 0; i < 4; ++i)
    #pragma unroll
    for (int j = 0; j < 4; ++j) acc[i][j] = (f32x4){0.f,0.f,0.f,0.f};

  const int srow = l >> 2;
  const int scol = (l & 3) * 8;

  for (int kt = 0; kt < 1024; kt += BK){
    GLD16(Ab + (size_t)(m0 + w*32 +      srow)*1024 + kt + scol, &At[(w*32)*BK]);
    GLD16(Ab + (size_t)(m0 + w*32 + 16 + srow)*1024 + kt + scol, &At[(w*32+16)*BK]);
    GLD16(WT + (size_t)(n0 + w*32 +      srow)*1024 + kt + scol, &Bt[(w*32)*BK]);
    GLD16(WT + (size_t)(n0 + w*32 + 16 + srow)*1024 + kt + scol, &Bt[(w*32+16)*BK]);
    __syncthreads();
    bf16x8 af[4], bf[4];
    #pragma unroll
    for (int i = 0; i < 4; ++i)
      af[i] = *(const bf16x8*)&At[(wr*64 + i*16 + lq)*BK + lh*8];
    #pragma unroll
    for (int j = 0; j < 4; ++j)
      bf[j] = *(const bf16x8*)&Bt[(wc*64 + j*16 + lq)*BK + lh*8];
    #pragma unroll
    for (int i = 0; i < 4; ++i)
      #pragma unroll
      for (int j = 0; j < 4; ++j)
        acc[i][j] = __builtin_amdgcn_mfma_f32_16x16x32_bf16(af[i], bf[j], acc[i][j], 0, 0, 0);
    __syncthreads();
  }
  #pragma unroll
  for (int i = 0; i < 4; ++i){
    #pragma unroll
    for (int j = 0; j < 4; ++j){
      #pragma unroll
      for (int r = 0; r < 4; ++r){
        int m = m0 + wr*64 + i*16 + (l>>4)*4 + r;
        int n = n0 + wc*64 + j*16 + (l&15);
        float v = acc[i][j][r] + bqkv[n];
        if (j == 0){   // rotary dims d = lq < 16
          float partner = __shfl_xor(v, 8);
          int s = m & 2047;
          float pos = (float)pos_ids[s];
          float fr = exp2f(-1.6609640474436813f * (float)(l & 7));
          float th = pos * fr;
          float sn = __sinf(th), cn = __cosf(th);
          v = ((l & 8) == 0) ? (v*cn - partner*sn) : (v*cn + partner*sn);
        }
        int b = m >> 11, s2 = m & 2047;
        int tsel = n >> 10; int nq = n & 1023;
        int h = nq >> 6, d = nq & 63;
        unsigned short* dst = tsel ? Kb : Qb;
        dst[((size_t)(b*16 + h)*S_ + s2)*64 + d] = f2bf(v);
      }
    }
  }
}

// ---------------- 4a: full-chip E + rinv precompute (R19: balanced bi).
#define KST2 66
#define EST 68
__launch_bounds__(256, 4)
__global__ void k_scores(const unsigned short* __restrict__ Qb,
                         const unsigned short* __restrict__ Kb,
                         unsigned short* __restrict__ Eg,
                         float* __restrict__ rinvg){
  __shared__ unsigned short Ks[2][64*KST2];
  __shared__ unsigned short Es[4][16*EST];
  __shared__ float dsh[4][16];
  const int q = blockIdx.x >> 5, bh = blockIdx.x & 31;
  const int qm = q & 7, qk = q >> 3;
  const int bi = (qk == 0) ? qm : (qk == 1) ? (15 - qm)
               : (qk == 2) ? (16 + qm) : (31 - qm);
  const unsigned short* Qh = Qb + (size_t)bh * S_ * 64;
  const unsigned short* Kh = Kb + (size_t)bh * S_ * 64;
  const int tid = threadIdx.x, w = tid >> 6, l = tid & 63;
  const int lq = l & 15, lh = l >> 4;
  const unsigned short* qp = Qh + (size_t)(bi*64 + w*16 + lq)*64 + lh*8;
  bf16x8 qf0 = *(const bf16x8*)(qp);
  bf16x8 qf1 = *(const bf16x8*)(qp + 32);
  float dacc[4] = {0.f,0.f,0.f,0.f};
  unsigned short* Etile0 = Eg + ((size_t)bh*528 + (size_t)(bi*(bi+1)/2))*4096;
  const int srow = tid >> 2, sc = (tid & 3)*16;

  {
    const unsigned short* src = Kh + (size_t)srow*64 + sc;
    *(int4*)&Ks[0][srow*KST2 + sc]     = *(const int4*)(src);
    *(int4*)&Ks[0][srow*KST2 + sc + 8] = *(const int4*)(src + 8);
  }
  __syncthreads();

  for (int bj = 0; bj <= bi; ++bj){
    const int cur = bj & 1;
    int4 nk0, nk1;
    if (bj < bi){
      const unsigned short* src = Kh + (size_t)((bj+1)*64 + srow)*64 + sc;
      nk0 = *(const int4*)(src);
      nk1 = *(const int4*)(src + 8);
    }
    unsigned short* Et = Etile0 + (size_t)bj*4096 + w*1024;
    const bool diag = (bj == bi);
    #pragma unroll
    for (int ct = 0; ct < 4; ++ct){
      bf16x8 b0 = *(const bf16x8*)&Ks[cur][(ct*16 + lq)*KST2 + lh*8];
      bf16x8 b1 = *(const bf16x8*)&Ks[cur][(ct*16 + lq)*KST2 + 32 + lh*8];
      f32x4 a = (f32x4){0.f,0.f,0.f,0.f};
      a = __builtin_amdgcn_mfma_f32_16x16x32_bf16(qf0, b0, a, 0, 0, 0);
      a = __builtin_amdgcn_mfma_f32_16x16x32_bf16(qf1, b1, a, 0, 0, 0);
      #pragma unroll
      for (int r = 0; r < 4; ++r){
        float e = __expf(a[r] * SCALEF);
        unsigned short eb = f2bf_trunc(e);
        int rrow = lh*4 + r, col = ct*16 + lq;
        Es[w][rrow*EST + col] = eb;
        float ev = bf2f(eb);
        int grow = w*16 + rrow;
        if (!diag || col < grow) dacc[r] += ev;
        if (diag && col == grow) dsh[w][rrow] = ev;
      }
    }
    #pragma unroll
    for (int it = 0; it < 2; ++it){
      int row = it*8 + (l >> 3), eo = (l & 7)*8;
      *(int4*)(Et + row*64 + eo) = *(const int4*)&Es[w][row*EST + eo];
    }
    if (bj < bi){
      *(int4*)&Ks[cur^1][srow*KST2 + sc]     = nk0;
      *(int4*)&Ks[cur^1][srow*KST2 + sc + 8] = nk1;
    }
    __syncthreads();
  }
  #pragma unroll
  for (int r = 0; r < 4; ++r){
    float d = dacc[r];
    #pragma unroll
    for (int mm = 1; mm < 16; mm <<= 1) d += __shfl_xor(d, mm);
    float dE = dsh[w][lh*4 + r];
    float den = fmaf(EPSF, d + dE, d);
    float rv = 1.0f / den;
    if (lq == 0)
      rinvg[(size_t)bh*S_ + bi*64 + w*16 + lh*4 + r] = rv;
  }
}

// ---------------- 4a': per-block unit-lower-triangular inverse (R17).
__global__ __launch_bounds__(64)
void k_dinv(const unsigned short* __restrict__ Eg,
            const float* __restrict__ rinvg,
            unsigned short* __restrict__ Dg){
  __shared__ float As[64*65];
  const int bh = blockIdx.x >> 5, bi = blockIdx.x & 31;
  const unsigned short* Et =
      Eg + ((size_t)bh*528 + (size_t)(bi*(bi+1)/2) + bi)*4096;
  const int c = threadIdx.x;
  for (int r = 0; r < 64; ++r){
    float rv = rinvg[(size_t)bh*S_ + bi*64 + r];
    float e = bf2f(Et[(r>>4)*1024 + (r&15)*64 + c]);
    As[r*65 + c] = (c < r) ? e * rv : 0.f;
  }
  __syncthreads();
  float X[64];
  #pragma unroll
  for (int r = 0; r < 64; ++r){
    float acc = (r == c) ? 1.f : 0.f;
    #pragma unroll
    for (int k = 0; k < r; ++k)
      acc = fmaf(As[r*65 + k], X[k], acc);
    X[r] = acc;
  }
  unsigned short* dt = Dg + (size_t)blockIdx.x * 4096;
  #pragma unroll
  for (int r = 0; r < 64; ++r)
    dt[(r>>4)*1024 + (r&15)*64 + c] = f2bf(X[r]);
}

// ---------------- 4b: striped recurrence v4 — 8 stripes/head (256 WGs, R17).
__global__ __launch_bounds__(512)
__attribute__((amdgpu_waves_per_eu(2, 2)))
void k_recur3(const unsigned short* __restrict__ Eg,
              const unsigned short* __restrict__ Dg,
              const float* __restrict__ rinvg,
              float* __restrict__ c_c,
              float* __restrict__ c_g){
  __shared__ float Pa[256];     // owned block o at Pa[o*64+row]
  __shared__ float rso[256];
  __shared__ float csl[2][64];
  __shared__ float bb[64];
  const int bh = blockIdx.x & 31, s = blockIdx.x >> 5;
  const unsigned short* Eh = Eg + (size_t)bh * 528 * 4096;
  const int tid = threadIdx.x, w = tid >> 6, l = tid & 63;
  const int lq = l & 15, lh = l >> 4;

  if (tid < 256){
    Pa[tid] = 0.f;
    rso[tid] = rinvg[(size_t)bh*S_ + (s + 8*(tid >> 6))*64 + l];
  }
  __syncthreads();

  bf16x8 dv0[4], dv1[4];        // wave0: Dinv tile of next owned block
  if (w == 0){
    const unsigned short* dt = Dg + (size_t)(bh*32 + s)*4096;
    #pragma unroll
    for (int q = 0; q < 4; ++q){
      dv0[q] = *(const bf16x8*)(dt + q*1024 + lq*64 + lh*8);
      dv1[q] = *(const bf16x8*)(dt + q*1024 + lq*64 + 32 + lh*8);
    }
  }

  bf16x8 dA0[3], dA1[3], dB0[3], dB1[3];   // deferred staging ping-pong
  bf16x8 ug0, ug1;                          // urgent tile regs (waves 1-4)
  const int lastc = s + 24;

  auto load_def = [&](int BJ, bf16x8 (&D0)[3], bf16x8 (&D1)[3]){
    int o0 = (BJ >= s) ? (((BJ - s) >> 3) + 1) : 0;
    int ex = (((BJ + 1) & 7) == s) ? 1 : 0;
    int nd = (4 - o0 - ex) * 4;
    if (w >= 1){
      #pragma unroll
      for (int k = 0; k < 3; ++k){
        int t = (w - 1) + k*7;
        if (t < nd){
          int ob = o0 + ex + (t >> 2);
          int bi = s + 8*ob;
          const unsigned short* tp =
              Eh + ((size_t)(bi*(bi+1)/2) + BJ)*4096 + (size_t)(t & 3)*1024;
          D0[k] = *(const bf16x8*)(tp + lq*64 + lh*8);
          D1[k] = *(const bf16x8*)(tp + lq*64 + 32 + lh*8);
        }
      }
      if (ex && w <= 4){
        int bi = BJ + 1;
        const unsigned short* tp =
            Eh + ((size_t)(bi*(bi+1)/2) + BJ)*4096 + (size_t)(w-1)*1024;
        ug0 = *(const bf16x8*)(tp + lq*64 + lh*8);
        ug1 = *(const bf16x8*)(tp + lq*64 + 32 + lh*8);
      }
    }
  };

  auto fold_def = [&](int BJP, bf16x8 (&D0)[3], bf16x8 (&D1)[3], int buf){
    int o0 = (BJP >= s) ? (((BJP - s) >> 3) + 1) : 0;
    int ex = (((BJP + 1) & 7) == s) ? 1 : 0;
    int nd = (4 - o0 - ex) * 4;
    if (w >= 1 && nd > 0){
      bf16x8 dc0 = (bf16x8){0,0,0,0,0,0,0,0};
      bf16x8 dc1 = (bf16x8){0,0,0,0,0,0,0,0};
      if (lq == 0){
        #pragma unroll
        for (int e = 0; e < 8; ++e){
          dc0[e] = (short)f2bf(csl[buf][lh*8 + e]);
          dc1[e] = (short)f2bf(csl[buf][32 + lh*8 + e]);
        }
      }
      #pragma unroll
      for (int k = 0; k < 3; ++k){
        int t = (w - 1) + k*7;
        if (t < nd){
          f32x4 o = (f32x4){0.f,0.f,0.f,0.f};
          o = __builtin_amdgcn_mfma_f32_16x16x32_bf16(D0[k], dc0, o, 0, 0, 0);
          o = __builtin_amdgcn_mfma_f32_16x16x32_bf16(D1[k], dc1, o, 0, 0, 0);
          if (lq == 0){
            int ob = o0 + ex + (t >> 2);
            float* base = Pa + ob*64 + (t & 3)*16 + lh*4;
            float4 v = *(float4*)base;
            v.x += o[0]; v.y += o[1]; v.z += o[2]; v.w += o[3];
            *(float4*)base = v;
          }
        }
      }
    }
  };

  auto iter = [&](int BJ, bf16x8 (&DL0)[3], bf16x8 (&DL1)[3],
                          bf16x8 (&DF0)[3], bf16x8 (&DF1)[3]){
    const int cur = BJ & 1;
    load_def(BJ, DL0, DL1);
    const int ex = (((BJ + 1) & 7) == s) ? 1 : 0;
    if (w == 0){
      if ((BJ & 7) == s){
        // matvec solve: c_blk = Dinv @ (rinv .* Pa), b0 := 1 at global row 0
        const int o = (BJ - s) >> 3;
        float bval = rso[o*64 + l] * Pa[o*64 + l];
        if (BJ == 0 && l == 0) bval = 1.0f;
        bb[l] = bval;
        bf16x8 uc0 = (bf16x8){0,0,0,0,0,0,0,0};
        bf16x8 uc1 = (bf16x8){0,0,0,0,0,0,0,0};
        if (lq == 0){
          #pragma unroll
          for (int e = 0; e < 8; ++e){
            uc0[e] = (short)f2bf(bb[lh*8 + e]);
            uc1[e] = (short)f2bf(bb[32 + lh*8 + e]);
          }
        }
        #pragma unroll
        for (int q = 0; q < 4; ++q){
          f32x4 o4 = (f32x4){0.f,0.f,0.f,0.f};
          o4 = __builtin_amdgcn_mfma_f32_16x16x32_bf16(dv0[q], uc0, o4, 0, 0, 0);
          o4 = __builtin_amdgcn_mfma_f32_16x16x32_bf16(dv1[q], uc1, o4, 0, 0, 0);
          if (lq == 0){
            #pragma unroll
            for (int r = 0; r < 4; ++r)
              csl[cur][q*16 + lh*4 + r] = o4[r];
          }
        }
        float cval = csl[cur][l];
        __hip_atomic_store((unsigned*)(c_c + (size_t)bh*S_ + BJ*64 + l),
                           __float_as_uint(cval),
                           __ATOMIC_RELAXED, __HIP_MEMORY_SCOPE_AGENT);
        c_g[((size_t)(bh >> 4)*S_ + (BJ*64 + l))*16 + (bh & 15)] = cval;
        int bn = BJ + 8;            // prefetch next owned Dinv tile
        if (bn <= lastc){
          const unsigned short* dt = Dg + (size_t)(bh*32 + bn)*4096;
          #pragma unroll
          for (int q = 0; q < 4; ++q){
            dv0[q] = *(const bf16x8*)(dt + q*1024 + lq*64 + lh*8);
            dv1[q] = *(const bf16x8*)(dt + q*1024 + lq*64 + 32 + lh*8);
          }
        }
      } else {
        const unsigned* pp = (const unsigned*)(c_c + (size_t)bh*S_ + BJ*64 + l);
        unsigned v = __hip_atomic_load(pp, __ATOMIC_RELAXED,
                                       __HIP_MEMORY_SCOPE_AGENT);
        while (!__all(v != 0u)){
          __builtin_amdgcn_s_sleep(2);
          v = __hip_atomic_load(pp, __ATOMIC_RELAXED,
                                __HIP_MEMORY_SCOPE_AGENT);
        }
        csl[cur][l] = __uint_as_float(v);
      }
    } else if (BJ >= 1){
      fold_def(BJ - 1, DF0, DF1, cur ^ 1);
    }
    __syncthreads();
    // phase B: urgent fold (col BJ -> block BJ+1), waves 1-4
    if (ex && w >= 1 && w <= 4){
      bf16x8 uc0 = (bf16x8){0,0,0,0,0,0,0,0};
      bf16x8 uc1 = (bf16x8){0,0,0,0,0,0,0,0};
      if (lq == 0){
        #pragma unroll
        for (int e = 0; e < 8; ++e){
          uc0[e] = (short)f2bf(csl[cur][lh*8 + e]);
          uc1[e] = (short)f2bf(csl[cur][32 + lh*8 + e]);
        }
      }
      f32x4 o = (f32x4){0.f,0.f,0.f,0.f};
      o = __builtin_amdgcn_mfma_f32_16x16x32_bf16(ug0, uc0, o, 0, 0, 0);
      o = __builtin_amdgcn_mfma_f32_16x16x32_bf16(ug1, uc1, o, 0, 0, 0);
      if (lq == 0){
        int ou = (BJ + 1 - s) >> 3;
        float* base = Pa + ou*64 + (w-1)*16 + lh*4;
        float4 v = *(float4*)base;
        v.x += o[0]; v.y += o[1]; v.z += o[2]; v.w += o[3];
        *(float4*)base = v;
      }
    }
    __syncthreads();
  };

  for (int bj = 0; bj <= lastc; bj += 2){
    iter(bj,     dA0, dA1, dB0, dB1);
    if (bj + 1 <= lastc)
      iter(bj+1, dB0, dB1, dA0, dA1);
  }
}

// ---------------- 5: out[b,s,n] = bd[n] + sum_h c[b,s,h] * U[b,h,n]
__global__ void k_out(const float* __restrict__ c_g, const float* __restrict__ U,
                      const float* __restrict__ bd, float* __restrict__ out){
  int bs = blockIdx.x; int b = bs >> 11;
  __shared__ float ch[16];
  if (threadIdx.x < 16) ch[threadIdx.x] = c_g[(size_t)bs*16 + threadIdx.x];
  __syncthreads();
  int n = threadIdx.x * 4;
  float4 acc = *(const float4*)(bd + n);
  #pragma unroll
  for (int h = 0; h < 16; ++h){
    float cc = ch[h];
    float4 u = *(const float4*)(U + ((size_t)(b*16 + h))*1024 + n);
    acc.x = fmaf(cc, u.x, acc.x); acc.y = fmaf(cc, u.y, acc.y);
    acc.z = fmaf(cc, u.z, acc.z); acc.w = fmaf(cc, u.w, acc.w);
  }
  *(float4*)(out + (size_t)bs*1024 + n) = acc;
}

extern "C" void kernel_launch(void* const* d_in, const int* in_sizes, int n_in,
                              void* d_out, int out_size, void* d_ws, size_t ws_size,
                              hipStream_t stream) {
  const float* hs   = (const float*)d_in[0];   // [2][2048][1024]
  const int*   pos  = (const int*)d_in[1];     // [2048]
  const float* Wqkv = (const float*)d_in[2];   // [1024][3072]
  const float* bqkv = (const float*)d_in[3];   // [3072]
  const float* Wd   = (const float*)d_in[4];   // [1024][1024]
  const float* bd   = (const float*)d_in[5];   // [1024]
  float* out = (float*)d_out;

  // workspace layout. Dg overlays Ab (dead after k_gemm_qk).
  char* ws = (char*)d_ws;
  unsigned short* Ab = (unsigned short*)(ws);                       // 8 MB
  unsigned short* Dg = (unsigned short*)(ws);                       // 8 MB (reuse)
  unsigned short* WT = (unsigned short*)(ws + (8u<<20));            // 4 MB
  unsigned short* Qb = (unsigned short*)(ws + (12u<<20));           // 8 MB
  unsigned short* Kb = (unsigned short*)(ws + (20u<<20));           // 8 MB
  float* c_g  = (float*)(ws + (28u<<20) + 0x10000);                 // 256 KB
  float* U    = (float*)(ws + (28u<<20) + 0x50000);                 // 128 KB
  float* rinvg= (float*)(ws + (28u<<20) + 0x80000);                 // 256 KB
  float* c_c  = (float*)(ws + (28u<<20) + 0xC0000);                 // 256 KB
  unsigned short* Eg = (unsigned short*)(ws + (29u<<20));           // 132 MB

  k_prep   <<<6240, 256, 0, stream>>>(hs, Wqkv, bqkv, Wd, Ab, WT, U, c_c);
  k_gemm_qk<<<dim3(16, 32), 256, 0, stream>>>(Ab, WT, bqkv, pos, Qb, Kb);
  k_scores <<<1024, 256, 0, stream>>>(Qb, Kb, Eg, rinvg);
  k_dinv   <<<1024, 64, 0, stream>>>(Eg, rinvg, Dg);
  k_recur3 <<<256, 512, 0, stream>>>(Eg, Dg, rinvg, c_c, c_g);
  k_out    <<<4096, 256, 0, stream>>>(c_g, U, bd, out);
}